// Round 9
// baseline (394.146 us; speedup 1.0000x reference)
//
#include <hip/hip_runtime.h>
#include <cstdint>
#include <cstddef>

#define D_MODEL 1024
#define N_HEADS 16
#define HEAD_DIM 64
#define BATCH 4
#define SEQ 2048
#define M_TOTAL (BATCH * SEQ)   // 8192

typedef __attribute__((ext_vector_type(8))) short bf16x8;    // 8 bf16 = 4 VGPRs
typedef __attribute__((ext_vector_type(4))) float f32x4;
typedef __attribute__((ext_vector_type(16))) float f32x16;

// scale = 1/sqrt(64) * log2(e), folded into Q projection (softmax in exp2 domain)
#define Q_SCALE 0.18033688011112042f

__device__ __forceinline__ unsigned short f2bu(float f) {   // RNE
    union { float f; unsigned u; } x; x.f = f;
    unsigned r = x.u + 0x7FFFu + ((x.u >> 16) & 1u);
    return (unsigned short)(r >> 16);
}
__device__ __forceinline__ float bu2f(unsigned hi16bits) {  // bits already in [31:16]
    union { unsigned u; float f; } x; x.u = hi16bits; return x.f;
}

__device__ __forceinline__ void async16(void* lds, const void* g) {
    __builtin_amdgcn_global_load_lds(
        (const __attribute__((address_space(1))) void*)g,
        (__attribute__((address_space(3))) void*)lds, 16, 0, 0);
}

// ---------------------------------------------------------------------------
// One fused fp32 -> bf16 cast for x + 4 weights (contiguous dst in ws).
// ---------------------------------------------------------------------------
__global__ __launch_bounds__(256) void cast_all(const float* __restrict__ x,
                                                const float* __restrict__ wq,
                                                const float* __restrict__ wk,
                                                const float* __restrict__ wv,
                                                const float* __restrict__ wo,
                                                unsigned short* __restrict__ dst) {
    const size_t NE = (size_t)M_TOTAL * D_MODEL;
    const size_t WE = (size_t)D_MODEL * D_MODEL;
    size_t i4 = (size_t)blockIdx.x * 256 + threadIdx.x;
    size_t e = i4 * 4;
    const float* src; size_t off;
    if (e < NE) { src = x; off = e; }
    else {
        size_t t = e - NE;
        int r = (int)(t / WE); off = t - (size_t)r * WE;
        src = (r == 0) ? wq : (r == 1) ? wk : (r == 2) ? wv : wo;
    }
    float4 v = *(const float4*)(src + off);
    ushort4 o;
    o.x = f2bu(v.x); o.y = f2bu(v.y); o.z = f2bu(v.z); o.w = f2bu(v.w);
    ((ushort4*)dst)[i4] = o;
}

// ---------------------------------------------------------------------------
// Fused Q/K/V projection (r8 version, T1 XCD remap, PASSED).
// ---------------------------------------------------------------------------
__global__ __launch_bounds__(256) void qkv_gemm(const unsigned short* __restrict__ X,
                                                const unsigned short* __restrict__ W0,
                                                const unsigned short* __restrict__ W1,
                                                const unsigned short* __restrict__ W2,
                                                unsigned short* __restrict__ Y0,
                                                unsigned short* __restrict__ Y1,
                                                unsigned short* __restrict__ Vt) {
    __shared__ short As[128 * 32];
    __shared__ short Bs[128 * 32];

    const int id = (int)blockIdx.x + 24 * (int)blockIdx.y;
    const int xcd = id & 7, slot = id >> 3;
    const int ty = xcd * 8 + slot / 24;        // row tile 0..63 (XCD-clustered)
    const int tx = slot % 24;                  // sel*8 + col tile

    const int sel = tx >> 3;
    const unsigned short* W = (sel == 0) ? W0 : (sel == 1) ? W1 : W2;
    const float scl = (sel == 0) ? Q_SCALE : 1.0f;

    const int tid = threadIdx.x;
    const int w = tid >> 6, lane = tid & 63, quad = lane >> 4, l15 = lane & 15;
    const int wm = w & 1, wn = w >> 1;
    const int rowBase = ty * 128;
    const int colBase = (tx & 7) * 128;

    f32x4 acc[4][4];
#pragma unroll
    for (int mi = 0; mi < 4; ++mi)
#pragma unroll
        for (int ni = 0; ni < 4; ++ni)
#pragma unroll
            for (int e = 0; e < 4; ++e) acc[mi][ni][e] = 0.f;

    for (int k0 = 0; k0 < 1024; k0 += 32) {
        __syncthreads();
#pragma unroll
        for (int l = 0; l < 2; ++l) {
            int c = tid + l * 256;
            int row = c >> 2, ccs = c & 3;
            int cc = ccs ^ ((row >> 1) & 3);
            async16((char*)As + c * 16, X + (size_t)(rowBase + row) * 1024 + k0 + cc * 8);
            async16((char*)Bs + c * 16, W + (size_t)(colBase + row) * 1024 + k0 + cc * 8);
        }
        __syncthreads();

        bf16x8 a[4], b[4];
#pragma unroll
        for (int mi = 0; mi < 4; ++mi) {
            int r = wm * 64 + mi * 16 + l15;
            int slt = quad ^ ((r >> 1) & 3);
            a[mi] = *(const bf16x8*)&As[r * 32 + slt * 8];
        }
#pragma unroll
        for (int ni = 0; ni < 4; ++ni) {
            int r = wn * 64 + ni * 16 + l15;
            int slt = quad ^ ((r >> 1) & 3);
            b[ni] = *(const bf16x8*)&Bs[r * 32 + slt * 8];
        }
#pragma unroll
        for (int mi = 0; mi < 4; ++mi)
#pragma unroll
            for (int ni = 0; ni < 4; ++ni)
                acc[mi][ni] = __builtin_amdgcn_mfma_f32_16x16x32_bf16(a[mi], b[ni], acc[mi][ni], 0, 0, 0);
    }

    if (sel != 2) {
        unsigned short* Y = (sel == 0) ? Y0 : Y1;
#pragma unroll
        for (int mi = 0; mi < 4; ++mi)
#pragma unroll
            for (int ni = 0; ni < 4; ++ni)
#pragma unroll
                for (int reg = 0; reg < 4; ++reg) {
                    int row = rowBase + wm * 64 + mi * 16 + quad * 4 + reg;
                    int col = colBase + wn * 64 + ni * 16 + l15;
                    Y[(size_t)row * 1024 + col] = f2bu(acc[mi][ni][reg] * scl);
                }
    } else {
        // transposed V write: Vt[((b*16+h)*64+d)*SEQ + s], 4 consecutive s per store
#pragma unroll
        for (int mi = 0; mi < 4; ++mi) {
            int row0 = rowBase + wm * 64 + mi * 16 + quad * 4;   // reg 0 row
            int bb = row0 >> 11;
            int s0 = row0 & 2047;
#pragma unroll
            for (int ni = 0; ni < 4; ++ni) {
                int col = colBase + wn * 64 + ni * 16 + l15;
                int hh = col >> 6, dd = col & 63;
                ushort4 pk;
                pk.x = f2bu(acc[mi][ni][0]); pk.y = f2bu(acc[mi][ni][1]);
                pk.z = f2bu(acc[mi][ni][2]); pk.w = f2bu(acc[mi][ni][3]);
                *(ushort4*)(Vt + (((size_t)bb * 16 + hh) * 64 + dd) * SEQ + s0) = pk;
            }
        }
    }
}

// ---------------------------------------------------------------------------
// Output projection (r8 version, T1 XCD remap, PASSED).
// ---------------------------------------------------------------------------
__global__ __launch_bounds__(256) void out_gemm(const unsigned short* __restrict__ X,
                                                const unsigned short* __restrict__ W,
                                                float* __restrict__ Y) {
    __shared__ short As[128 * 32];
    __shared__ short Bs[128 * 32];

    const int id = (int)blockIdx.x + 8 * (int)blockIdx.y;
    const int xcd = id & 7, slot = id >> 3;
    const int ty = xcd * 8 + (slot >> 3);
    const int tx = slot & 7;

    const int tid = threadIdx.x;
    const int w = tid >> 6, lane = tid & 63, quad = lane >> 4, l15 = lane & 15;
    const int wm = w & 1, wn = w >> 1;
    const int rowBase = ty * 128;
    const int colBase = tx * 128;

    f32x4 acc[4][4];
#pragma unroll
    for (int mi = 0; mi < 4; ++mi)
#pragma unroll
        for (int ni = 0; ni < 4; ++ni)
#pragma unroll
            for (int e = 0; e < 4; ++e) acc[mi][ni][e] = 0.f;

    for (int k0 = 0; k0 < 1024; k0 += 32) {
        __syncthreads();
#pragma unroll
        for (int l = 0; l < 2; ++l) {
            int c = tid + l * 256;
            int row = c >> 2, ccs = c & 3;
            int cc = ccs ^ ((row >> 1) & 3);
            async16((char*)As + c * 16, X + (size_t)(rowBase + row) * 1024 + k0 + cc * 8);
            async16((char*)Bs + c * 16, W + (size_t)(colBase + row) * 1024 + k0 + cc * 8);
        }
        __syncthreads();

        bf16x8 a[4], b[4];
#pragma unroll
        for (int mi = 0; mi < 4; ++mi) {
            int r = wm * 64 + mi * 16 + l15;
            int slt = quad ^ ((r >> 1) & 3);
            a[mi] = *(const bf16x8*)&As[r * 32 + slt * 8];
        }
#pragma unroll
        for (int ni = 0; ni < 4; ++ni) {
            int r = wn * 64 + ni * 16 + l15;
            int slt = quad ^ ((r >> 1) & 3);
            b[ni] = *(const bf16x8*)&Bs[r * 32 + slt * 8];
        }
#pragma unroll
        for (int mi = 0; mi < 4; ++mi)
#pragma unroll
            for (int ni = 0; ni < 4; ++ni)
                acc[mi][ni] = __builtin_amdgcn_mfma_f32_16x16x32_bf16(a[mi], b[ni], acc[mi][ni], 0, 0, 0);
    }

#pragma unroll
    for (int mi = 0; mi < 4; ++mi)
#pragma unroll
        for (int ni = 0; ni < 4; ++ni)
#pragma unroll
            for (int reg = 0; reg < 4; ++reg) {
                int row = rowBase + wm * 64 + mi * 16 + quad * 4 + reg;
                int col = colBase + wn * 64 + ni * 16 + l15;
                Y[(size_t)row * 1024 + col] = acc[mi][ni][reg];
            }
}

// ---------------------------------------------------------------------------
// Flash attention, KV-SPLIT: r5/r8 structure, but each (bh,pid) pair's key
// range is split across two blocks (half 0/1): block handles q-tiles
// {15-pid, pid} with kt in [half*(qt+1), half*(qt+1)+qt] -> EXACTLY 17
// iterations for all 1024 blocks. Grid (64, 16) = 4 blocks/CU co-resident
// (2x the wave count of r5's 512-block grid). Each half writes UNNORMALIZED
// partial O (bf16, CTX layout; half0 -> CTX region, half1 -> dead xb region)
// plus per-row (m,l) f32 (dead wqb region). flash_combine merges in-place.
// Everything else identical to r5 (PASSED): KVBLK=64, dbuf 1-barrier/iter,
// triangle guards, defer-max THR=8, v_cvt_pk pack, allSeq path, setprio.
// ---------------------------------------------------------------------------
__global__ __launch_bounds__(256, 4) void flash32(const unsigned short* __restrict__ Q,
                                                  const unsigned short* __restrict__ K,
                                                  const unsigned short* __restrict__ Vt,
                                                  const int* __restrict__ mask,
                                                  unsigned short* __restrict__ P0,
                                                  unsigned short* __restrict__ P1,
                                                  float2* __restrict__ ml) {
    __shared__ short lds[16384];           // K dbuf [0..8191], V dbuf [8192..16383] (shorts)
    __shared__ float biasS[2][64];
    __shared__ int allokS[2];
    __shared__ int okW[4];

    const int bh = blockIdx.x;             // 0..63 (same-bh blocks share an XCD)
    const int pid = (int)blockIdx.y & 7;   // 0..7
    const int kvHalf = (int)blockIdx.y >> 3;   // 0 = low keys, 1 = high keys
    const int b = bh >> 4;
    const int tid = threadIdx.x;
    const int w = tid >> 6, lane = tid & 63, l31 = lane & 31, lane5 = lane >> 5;

    const size_t qkBase = (size_t)b * SEQ * D_MODEL + (size_t)(bh & 15) * HEAD_DIM;
    const size_t vtBase = (size_t)bh * HEAD_DIM * SEQ;

    // ---- attention_mask is k-loop invariant: scan it once per block ----
    {
        int ok = 1;
        for (int i = tid; i < SEQ; i += 256) ok &= (mask[b * SEQ + i] != 0);
        unsigned long long bal = __ballot(ok != 0);
        if (lane == 0) okW[w] = (bal == ~0ull) ? 1 : 0;
    }
    __syncthreads();
    const int allSeq = okW[0] & okW[1] & okW[2] & okW[3];   // block-uniform

    // per-thread staging constants (chunk c = tid + l*256)
    int stp[2], stcc[2], stj[2];
#pragma unroll
    for (int l = 0; l < 2; ++l) {
        int c = tid + l * 256;
        int p = c >> 3, sl = c & 7;
        stp[l] = p;
        stcc[l] = sl ^ (p & 7);                                   // bank swizzle
        stj[l] = (p & 0x33) | ((p & 4) << 1) | ((p & 8) >> 1);    // swap bits 2,3
    }

    for (int phase = 0; phase < 2; ++phase) {
        const int qt = phase ? pid : 15 - pid;
        const int q0 = qt * 128;
        const int iq = q0 + w * 32 + l31;      // this lane's query row

        const int klo = kvHalf * (qt + 1);     // first k-tile of this half
        const int kend = klo + qt;             // last k-tile (inclusive): qt+1 tiles

        // Q fragments direct from global: B[n=i=l31][k=lane5*8+jj]
        bf16x8 qf[4];
#pragma unroll
        for (int ks = 0; ks < 4; ++ks)
            qf[ks] = *(const bf16x8*)(Q + qkBase + (size_t)iq * D_MODEL + ks * 16 + lane5 * 8);

        float mv = -INFINITY, lv = 0.f;
        f32x16 Ot[2];
#pragma unroll
        for (int dt = 0; dt < 2; ++dt)
#pragma unroll
            for (int e = 0; e < 16; ++e) Ot[dt][e] = 0.f;

        uint4 kreg[2], vreg[2];
        int mreg = 1;
        // prefetch tile klo
#pragma unroll
        for (int l = 0; l < 2; ++l) {
            kreg[l] = *(const uint4*)(K + qkBase + (size_t)(klo * 64 + stj[l]) * D_MODEL + stcc[l] * 8);
            vreg[l] = *(const uint4*)(Vt + vtBase + (size_t)stp[l] * SEQ + klo * 64 + stcc[l] * 8);
        }
        if (!allSeq && tid < 64) mreg = mask[b * SEQ + klo * 64 + tid];

        for (int kt = klo; kt <= kend; ++kt) {
            const int k0 = kt * 64;
            const int buf = kt & 1;
            // ---- stage tile kt into buf (regs -> LDS), prefetch kt+1 ----
#pragma unroll
            for (int l = 0; l < 2; ++l) {
                int c = tid + l * 256;
                *(uint4*)((char*)lds + buf * 8192 + c * 16) = kreg[l];
                *(uint4*)((char*)lds + 16384 + buf * 8192 + c * 16) = vreg[l];
            }
            if (!allSeq && tid < 64) {
                biasS[buf][tid] = mreg ? 0.f : -INFINITY;
                unsigned long long bal = __ballot(mreg != 0);
                if (tid == 0) allokS[buf] = (bal == ~0ull) ? 1 : 0;
            }
            if (kt < kend) {                   // prefetch next tile (overlaps compute)
                const int kn = k0 + 64;
#pragma unroll
                for (int l = 0; l < 2; ++l) {
                    kreg[l] = *(const uint4*)(K + qkBase + (size_t)(kn + stj[l]) * D_MODEL + stcc[l] * 8);
                    vreg[l] = *(const uint4*)(Vt + vtBase + (size_t)stp[l] * SEQ + kn + stcc[l] * 8);
                }
                if (!allSeq && tid < 64) mreg = mask[b * SEQ + kn + tid];
            }
            __syncthreads();                   // buf visible; buf reuse fenced by barrier(kt+1)

            if (64 * kt > q0 + 32 * w + 31) continue;   // wave-uniform: tile above causal diag

            const short* Ks = lds + buf * 4096;
            const short* Vs = lds + 8192 + buf * 4096;

            // wave-uniform active range (diagonal tile triangle)
            const int kHi = q0 + 32 * w + 31 - k0;           // >= 0 here
            const int nT = (kHi >= 32) ? 2 : 1;              // active 32-key QK sub-tiles
            const int nt = ((kHi >> 4) >= 3 ? 3 : (kHi >> 4)) + 1;  // active 16-key PV slots

            // ---- St = K Q^T (up to 8 MFMAs) -----------------------------
            f32x16 St[2];
            __builtin_amdgcn_s_setprio(1);
#pragma unroll
            for (int T = 0; T < 2; ++T) {
                if (T < nT) {
#pragma unroll
                    for (int e = 0; e < 16; ++e) St[T][e] = 0.f;
#pragma unroll
                    for (int ks = 0; ks < 4; ++ks) {
                        int p = T * 32 + l31;
                        int slot = (ks * 2 + lane5) ^ (p & 7);
                        bf16x8 a = *(const bf16x8*)&Ks[p * 64 + slot * 8];
                        St[T] = __builtin_amdgcn_mfma_f32_32x32x16_bf16(a, qf[ks], St[T], 0, 0, 0);
                    }
                }
            }
            __builtin_amdgcn_s_setprio(0);

            // ---- masking ------------------------------------------------
            const bool partial = (k0 + 63 > q0 + 32 * w);
            if (partial) {
#pragma unroll
                for (int T = 0; T < 2; ++T)
                    if (T < nT)
#pragma unroll
                        for (int r = 0; r < 16; ++r) {
                            int j = k0 + 32 * T + 16 * (r >> 3) + 8 * lane5 + (r & 7);
                            if (j > iq) St[T][r] = -INFINITY;
                        }
            }
            if (!allSeq && !allokS[buf]) {
#pragma unroll
                for (int T = 0; T < 2; ++T)
                    if (T < nT)
#pragma unroll
                        for (int r = 0; r < 16; ++r)
                            St[T][r] += biasS[buf][32 * T + 16 * (r >> 3) + 8 * lane5 + (r & 7)];
            }

            // ---- online softmax (defer-max THR=8, per-lane state) -------
            float tm[2];
#pragma unroll
            for (int T = 0; T < 2; ++T) {
                if (T < nT) {
                    float a0 = fmaxf(fmaxf(St[T][0], St[T][1]), fmaxf(St[T][2], St[T][3]));
                    float a1 = fmaxf(fmaxf(St[T][4], St[T][5]), fmaxf(St[T][6], St[T][7]));
                    float a2 = fmaxf(fmaxf(St[T][8], St[T][9]), fmaxf(St[T][10], St[T][11]));
                    float a3 = fmaxf(fmaxf(St[T][12], St[T][13]), fmaxf(St[T][14], St[T][15]));
                    tm[T] = fmaxf(fmaxf(a0, a1), fmaxf(a2, a3));
                } else tm[T] = -INFINITY;
            }
            float rm = fmaxf(tm[0], tm[1]);
            rm = fmaxf(rm, __shfl_xor(rm, 32));
            float mn = fmaxf(mv, rm);
            if (mn > mv + 8.f) {               // rare after warmup (also hits 1st tile)
                float al = exp2f(mv - mn);     // mv=-inf -> 0: correctly zeroes lv/Ot
                lv *= al;
#pragma unroll
                for (int dt = 0; dt < 2; ++dt)
#pragma unroll
                    for (int e = 0; e < 16; ++e) Ot[dt][e] *= al;
                mv = mn;
            }
            // exp2 vs (possibly stale) mv: P bounded by 2^8; -inf scores -> 0
            float rsp[2] = {0.f, 0.f};
#pragma unroll
            for (int T = 0; T < 2; ++T) {
                if (T < nT) {
#pragma unroll
                    for (int r = 0; r < 16; ++r) {
                        float pv = exp2f(St[T][r] - mv);
                        St[T][r] = pv;
                        rsp[T] += pv;
                    }
                }
            }
            float rs = rsp[0] + rsp[1];
            rs += __shfl_xor(rs, 32);
            lv += rs;

            // ---- pack P via v_cvt_pk_bf16_f32 (regs already B-frag order)
            bf16x8 pf[4];
#pragma unroll
            for (int t = 0; t < 4; ++t) {
                if (t < nt) {
                    const int T = t >> 1, hb = t & 1;
                    unsigned u0, u1, u2, u3;
                    asm("v_cvt_pk_bf16_f32 %0, %1, %2" : "=v"(u0)
                        : "v"(St[T][hb * 8 + 0]), "v"(St[T][hb * 8 + 1]));
                    asm("v_cvt_pk_bf16_f32 %0, %1, %2" : "=v"(u1)
                        : "v"(St[T][hb * 8 + 2]), "v"(St[T][hb * 8 + 3]));
                    asm("v_cvt_pk_bf16_f32 %0, %1, %2" : "=v"(u2)
                        : "v"(St[T][hb * 8 + 4]), "v"(St[T][hb * 8 + 5]));
                    asm("v_cvt_pk_bf16_f32 %0, %1, %2" : "=v"(u3)
                        : "v"(St[T][hb * 8 + 6]), "v"(St[T][hb * 8 + 7]));
                    union { unsigned u[4]; bf16x8 v; } pk;
                    pk.u[0] = u0; pk.u[1] = u1; pk.u[2] = u2; pk.u[3] = u3;
                    pf[t] = pk.v;
                }
            }

            // ---- Ot += V^T P^T (up to 8 MFMAs) --------------------------
            __builtin_amdgcn_s_setprio(1);
#pragma unroll
            for (int dt = 0; dt < 2; ++dt)
#pragma unroll
                for (int t = 0; t < 4; ++t) {
                    if (t < nt) {
                        int p = dt * 32 + l31;
                        int slot = (t * 2 + lane5) ^ (p & 7);
                        bf16x8 a = *(const bf16x8*)&Vs[p * 64 + slot * 8];
                        Ot[dt] = __builtin_amdgcn_mfma_f32_32x32x16_bf16(a, pf[t], Ot[dt], 0, 0, 0);
                    }
                }
            __builtin_amdgcn_s_setprio(0);
        }

        // ---- epilogue: store UNNORMALIZED O (bf16) via LDS transpose ----
        __syncthreads();                       // all waves done with K/V buffers
        unsigned short* dst = kvHalf ? P1 : P0;
#pragma unroll
        for (int dt = 0; dt < 2; ++dt)
#pragma unroll
            for (int k = 0; k < 8; ++k) {
                int r0 = 2 * k;
                int d = (r0 & 3) + 4 * lane5 + 8 * (r0 >> 2) + 32 * dt;
                unsigned lo = f2bu(Ot[dt][r0]);
                unsigned hi = f2bu(Ot[dt][r0 + 1]);
                *(unsigned*)&lds[(w * 32 + l31) * 72 + d] = lo | (hi << 16);
            }
        if (lane < 32) {                       // per-row (m, l); rows w*32+l31
            float2 v; v.x = mv; v.y = lv;
            ml[(((size_t)(kvHalf * 4 + b)) * 16 + (bh & 15)) * 2048 + (q0 + w * 32 + l31)] = v;
        }
        __syncthreads();
#pragma unroll
        for (int k = 0; k < 4; ++k) {
            int id = tid + k * 256;
            int r = id >> 3, cc = id & 7;
            uint4 v = *(const uint4*)&lds[r * 72 + cc * 8];
            *(uint4*)(dst + qkBase + (size_t)(q0 + r) * D_MODEL + cc * 8) = v;
        }
        __syncthreads();                       // protect epilogue reads from next phase's staging
    }
}

// ---------------------------------------------------------------------------
// Combine the two KV-halves in-place on CTX (= P0):
//   O = (O0*e2(m0-m) + O1*e2(m1-m)) / (l0*e2(m0-m) + l1*e2(m1-m)), m=max.
// Elementwise, 8 bf16 per thread; f0/f1 uniform per (row, head).
// ---------------------------------------------------------------------------
__global__ __launch_bounds__(256) void flash_combine(unsigned short* __restrict__ CTX,
                                                     const unsigned short* __restrict__ P1,
                                                     const float2* __restrict__ ml) {
    size_t i8 = (size_t)blockIdx.x * 256 + threadIdx.x;   // 1,048,576 total
    size_t e = i8 * 8;
    int row = (int)(e >> 10);          // global row 0..8191
    int col = (int)(e & 1023);
    int head = col >> 6;
    int b = row >> 11, s = row & 2047;

    float2 a0 = ml[(((size_t)b) * 16 + head) * 2048 + s];
    float2 a1 = ml[(((size_t)(4 + b)) * 16 + head) * 2048 + s];
    float m = fmaxf(a0.x, a1.x);
    float f0 = exp2f(a0.x - m);        // m0=-inf impossible (low half has kt=0)
    float f1 = exp2f(a1.x - m);        // m1=-inf -> 0 (empty high half)
    float l = a0.y * f0 + a1.y * f1;
    float inv = 1.f / l;
    f0 *= inv; f1 *= inv;

    uint4 u0 = *(const uint4*)(CTX + e);
    uint4 u1 = *(const uint4*)(P1 + e);
    unsigned o[4];
    unsigned uu0[4] = {u0.x, u0.y, u0.z, u0.w};
    unsigned uu1[4] = {u1.x, u1.y, u1.z, u1.w};
#pragma unroll
    for (int j = 0; j < 4; ++j) {
        float xl = bu2f(uu0[j] << 16) * f0 + bu2f(uu1[j] << 16) * f1;
        float xh = bu2f(uu0[j] & 0xFFFF0000u) * f0 + bu2f(uu1[j] & 0xFFFF0000u) * f1;
        o[j] = f2bu(xl) | ((unsigned)f2bu(xh) << 16);
    }
    uint4 ov; ov.x = o[0]; ov.y = o[1]; ov.z = o[2]; ov.w = o[3];
    *(uint4*)(CTX + e) = ov;
}

// ---------------------------------------------------------------------------
extern "C" void kernel_launch(void* const* d_in, const int* in_sizes, int n_in,
                              void* d_out, int out_size, void* d_ws, size_t ws_size,
                              hipStream_t stream) {
    const float* x  = (const float*)d_in[0];
    const int* mask = (const int*)d_in[1];
    const float* wq = (const float*)d_in[2];
    const float* wk = (const float*)d_in[3];
    const float* wv = (const float*)d_in[4];
    const float* wo = (const float*)d_in[5];
    float* out = (float*)d_out;

    const size_t NE = (size_t)M_TOTAL * D_MODEL;
    const size_t WE = (size_t)D_MODEL * D_MODEL;
    unsigned short* ws  = (unsigned short*)d_ws;
    unsigned short* xb  = ws;            // dead after qkv_gemm -> P1 partial buffer
    unsigned short* wqb = xb + NE;       // dead after qkv_gemm -> ml buffer (2 MB exact)
    unsigned short* wkb = wqb + WE;
    unsigned short* wvb = wkb + WE;
    unsigned short* wob = wvb + WE;
    unsigned short* Qb  = wob + WE;
    unsigned short* Kb  = Qb + NE;
    unsigned short* Vtb = Kb + NE;
    unsigned short* CTX = Vtb + NE;      // half-0 partial, then combined in-place

    cast_all<<<(int)((NE + 4 * WE) / 4 / 256), 256, 0, stream>>>(x, wq, wk, wv, wo, ws);

    qkv_gemm<<<dim3(24, M_TOTAL / 128), 256, 0, stream>>>(xb, wqb, wkb, wvb, Qb, Kb, Vtb);

    flash32<<<dim3(64, 16), 256, 0, stream>>>(Qb, Kb, Vtb, mask, CTX, xb, (float2*)wqb);

    flash_combine<<<(int)(NE / 8 / 256), 256, 0, stream>>>(CTX, xb, (const float2*)wqb);

    out_gemm<<<dim3(D_MODEL / 128, M_TOTAL / 128), 256, 0, stream>>>(CTX, wob, out);
}

// Round 10
// 331.792 us; speedup vs baseline: 1.1879x; 1.1879x over previous
//
#include <hip/hip_runtime.h>
#include <cstdint>
#include <cstddef>

#define D_MODEL 1024
#define N_HEADS 16
#define HEAD_DIM 64
#define BATCH 4
#define SEQ 2048
#define M_TOTAL (BATCH * SEQ)   // 8192

typedef __attribute__((ext_vector_type(8))) short bf16x8;    // 8 bf16 = 4 VGPRs
typedef __attribute__((ext_vector_type(4))) float f32x4;
typedef __attribute__((ext_vector_type(16))) float f32x16;

// scale = 1/sqrt(64) * log2(e), folded into Q projection (softmax in exp2 domain)
#define Q_SCALE 0.18033688011112042f

__device__ __forceinline__ unsigned short f2bu(float f) {   // RNE
    union { float f; unsigned u; } x; x.f = f;
    unsigned r = x.u + 0x7FFFu + ((x.u >> 16) & 1u);
    return (unsigned short)(r >> 16);
}
__device__ __forceinline__ float bu2f(unsigned hi16bits) {  // bits already in [31:16]
    union { unsigned u; float f; } x; x.u = hi16bits; return x.f;
}

__device__ __forceinline__ void async16(void* lds, const void* g) {
    __builtin_amdgcn_global_load_lds(
        (const __attribute__((address_space(1))) void*)g,
        (__attribute__((address_space(3))) void*)lds, 16, 0, 0);
}

// ---------------------------------------------------------------------------
// One fused fp32 -> bf16 cast for x + 4 weights (contiguous dst in ws).
// ---------------------------------------------------------------------------
__global__ __launch_bounds__(256) void cast_all(const float* __restrict__ x,
                                                const float* __restrict__ wq,
                                                const float* __restrict__ wk,
                                                const float* __restrict__ wv,
                                                const float* __restrict__ wo,
                                                unsigned short* __restrict__ dst) {
    const size_t NE = (size_t)M_TOTAL * D_MODEL;
    const size_t WE = (size_t)D_MODEL * D_MODEL;
    size_t i4 = (size_t)blockIdx.x * 256 + threadIdx.x;
    size_t e = i4 * 4;
    const float* src; size_t off;
    if (e < NE) { src = x; off = e; }
    else {
        size_t t = e - NE;
        int r = (int)(t / WE); off = t - (size_t)r * WE;
        src = (r == 0) ? wq : (r == 1) ? wk : (r == 2) ? wv : wo;
    }
    float4 v = *(const float4*)(src + off);
    ushort4 o;
    o.x = f2bu(v.x); o.y = f2bu(v.y); o.z = f2bu(v.z); o.w = f2bu(v.w);
    ((ushort4*)dst)[i4] = o;
}

// ---------------------------------------------------------------------------
// Fused Q/K/V projection (r8 version, T1 XCD remap, PASSED).
// ---------------------------------------------------------------------------
__global__ __launch_bounds__(256) void qkv_gemm(const unsigned short* __restrict__ X,
                                                const unsigned short* __restrict__ W0,
                                                const unsigned short* __restrict__ W1,
                                                const unsigned short* __restrict__ W2,
                                                unsigned short* __restrict__ Y0,
                                                unsigned short* __restrict__ Y1,
                                                unsigned short* __restrict__ Vt) {
    __shared__ short As[128 * 32];
    __shared__ short Bs[128 * 32];

    const int id = (int)blockIdx.x + 24 * (int)blockIdx.y;
    const int xcd = id & 7, slot = id >> 3;
    const int ty = xcd * 8 + slot / 24;        // row tile 0..63 (XCD-clustered)
    const int tx = slot % 24;                  // sel*8 + col tile

    const int sel = tx >> 3;
    const unsigned short* W = (sel == 0) ? W0 : (sel == 1) ? W1 : W2;
    const float scl = (sel == 0) ? Q_SCALE : 1.0f;

    const int tid = threadIdx.x;
    const int w = tid >> 6, lane = tid & 63, quad = lane >> 4, l15 = lane & 15;
    const int wm = w & 1, wn = w >> 1;
    const int rowBase = ty * 128;
    const int colBase = (tx & 7) * 128;

    f32x4 acc[4][4];
#pragma unroll
    for (int mi = 0; mi < 4; ++mi)
#pragma unroll
        for (int ni = 0; ni < 4; ++ni)
#pragma unroll
            for (int e = 0; e < 4; ++e) acc[mi][ni][e] = 0.f;

    for (int k0 = 0; k0 < 1024; k0 += 32) {
        __syncthreads();
#pragma unroll
        for (int l = 0; l < 2; ++l) {
            int c = tid + l * 256;
            int row = c >> 2, ccs = c & 3;
            int cc = ccs ^ ((row >> 1) & 3);
            async16((char*)As + c * 16, X + (size_t)(rowBase + row) * 1024 + k0 + cc * 8);
            async16((char*)Bs + c * 16, W + (size_t)(colBase + row) * 1024 + k0 + cc * 8);
        }
        __syncthreads();

        bf16x8 a[4], b[4];
#pragma unroll
        for (int mi = 0; mi < 4; ++mi) {
            int r = wm * 64 + mi * 16 + l15;
            int slt = quad ^ ((r >> 1) & 3);
            a[mi] = *(const bf16x8*)&As[r * 32 + slt * 8];
        }
#pragma unroll
        for (int ni = 0; ni < 4; ++ni) {
            int r = wn * 64 + ni * 16 + l15;
            int slt = quad ^ ((r >> 1) & 3);
            b[ni] = *(const bf16x8*)&Bs[r * 32 + slt * 8];
        }
#pragma unroll
        for (int mi = 0; mi < 4; ++mi)
#pragma unroll
            for (int ni = 0; ni < 4; ++ni)
                acc[mi][ni] = __builtin_amdgcn_mfma_f32_16x16x32_bf16(a[mi], b[ni], acc[mi][ni], 0, 0, 0);
    }

    if (sel != 2) {
        unsigned short* Y = (sel == 0) ? Y0 : Y1;
#pragma unroll
        for (int mi = 0; mi < 4; ++mi)
#pragma unroll
            for (int ni = 0; ni < 4; ++ni)
#pragma unroll
                for (int reg = 0; reg < 4; ++reg) {
                    int row = rowBase + wm * 64 + mi * 16 + quad * 4 + reg;
                    int col = colBase + wn * 64 + ni * 16 + l15;
                    Y[(size_t)row * 1024 + col] = f2bu(acc[mi][ni][reg] * scl);
                }
    } else {
        // transposed V write: Vt[((b*16+h)*64+d)*SEQ + s], 4 consecutive s per store
#pragma unroll
        for (int mi = 0; mi < 4; ++mi) {
            int row0 = rowBase + wm * 64 + mi * 16 + quad * 4;   // reg 0 row
            int bb = row0 >> 11;
            int s0 = row0 & 2047;
#pragma unroll
            for (int ni = 0; ni < 4; ++ni) {
                int col = colBase + wn * 64 + ni * 16 + l15;
                int hh = col >> 6, dd = col & 63;
                ushort4 pk;
                pk.x = f2bu(acc[mi][ni][0]); pk.y = f2bu(acc[mi][ni][1]);
                pk.z = f2bu(acc[mi][ni][2]); pk.w = f2bu(acc[mi][ni][3]);
                *(ushort4*)(Vt + (((size_t)bb * 16 + hh) * 64 + dd) * SEQ + s0) = pk;
            }
        }
    }
}

// ---------------------------------------------------------------------------
// Output projection (r8 version, T1 XCD remap, PASSED).
// ---------------------------------------------------------------------------
__global__ __launch_bounds__(256) void out_gemm(const unsigned short* __restrict__ X,
                                                const unsigned short* __restrict__ W,
                                                float* __restrict__ Y) {
    __shared__ short As[128 * 32];
    __shared__ short Bs[128 * 32];

    const int id = (int)blockIdx.x + 8 * (int)blockIdx.y;
    const int xcd = id & 7, slot = id >> 3;
    const int ty = xcd * 8 + (slot >> 3);
    const int tx = slot & 7;

    const int tid = threadIdx.x;
    const int w = tid >> 6, lane = tid & 63, quad = lane >> 4, l15 = lane & 15;
    const int wm = w & 1, wn = w >> 1;
    const int rowBase = ty * 128;
    const int colBase = tx * 128;

    f32x4 acc[4][4];
#pragma unroll
    for (int mi = 0; mi < 4; ++mi)
#pragma unroll
        for (int ni = 0; ni < 4; ++ni)
#pragma unroll
            for (int e = 0; e < 4; ++e) acc[mi][ni][e] = 0.f;

    for (int k0 = 0; k0 < 1024; k0 += 32) {
        __syncthreads();
#pragma unroll
        for (int l = 0; l < 2; ++l) {
            int c = tid + l * 256;
            int row = c >> 2, ccs = c & 3;
            int cc = ccs ^ ((row >> 1) & 3);
            async16((char*)As + c * 16, X + (size_t)(rowBase + row) * 1024 + k0 + cc * 8);
            async16((char*)Bs + c * 16, W + (size_t)(colBase + row) * 1024 + k0 + cc * 8);
        }
        __syncthreads();

        bf16x8 a[4], b[4];
#pragma unroll
        for (int mi = 0; mi < 4; ++mi) {
            int r = wm * 64 + mi * 16 + l15;
            int slt = quad ^ ((r >> 1) & 3);
            a[mi] = *(const bf16x8*)&As[r * 32 + slt * 8];
        }
#pragma unroll
        for (int ni = 0; ni < 4; ++ni) {
            int r = wn * 64 + ni * 16 + l15;
            int slt = quad ^ ((r >> 1) & 3);
            b[ni] = *(const bf16x8*)&Bs[r * 32 + slt * 8];
        }
#pragma unroll
        for (int mi = 0; mi < 4; ++mi)
#pragma unroll
            for (int ni = 0; ni < 4; ++ni)
                acc[mi][ni] = __builtin_amdgcn_mfma_f32_16x16x32_bf16(a[mi], b[ni], acc[mi][ni], 0, 0, 0);
    }

#pragma unroll
    for (int mi = 0; mi < 4; ++mi)
#pragma unroll
        for (int ni = 0; ni < 4; ++ni)
#pragma unroll
            for (int reg = 0; reg < 4; ++reg) {
                int row = rowBase + wm * 64 + mi * 16 + quad * 4 + reg;
                int col = colBase + wn * 64 + ni * 16 + l15;
                Y[(size_t)row * 1024 + col] = acc[mi][ni][reg];
            }
}

// ---------------------------------------------------------------------------
// Flash attention, KV-SPLIT (r9 structure, PASSED correctness) with the
// launch-bounds spill fixed: plain __launch_bounds__(256). r9's (256,4)
// made the allocator target 64 VGPR -> St/Ot spilled to scratch -> 700 MB
// of HBM scratch traffic -> 195 us. At the natural ~120 VGPR the 1024-block
// grid still gets 4 blocks/CU (floor(512/120)=4 waves/SIMD; 4*33.8KB<160KB).
// Block (bh, pid, half): q-tiles {15-pid, pid}, kt in [half*(qt+1), ...+qt]
// -> exactly 17 iterations for all 1024 blocks. Unnormalized partial O ->
// CTX / xb regions; (m,l) -> wqb region; flash_combine merges in-place.
// ---------------------------------------------------------------------------
__global__ __launch_bounds__(256) void flash32(const unsigned short* __restrict__ Q,
                                               const unsigned short* __restrict__ K,
                                               const unsigned short* __restrict__ Vt,
                                               const int* __restrict__ mask,
                                               unsigned short* __restrict__ P0,
                                               unsigned short* __restrict__ P1,
                                               float2* __restrict__ ml) {
    __shared__ short lds[16384];           // K dbuf [0..8191], V dbuf [8192..16383] (shorts)
    __shared__ float biasS[2][64];
    __shared__ int allokS[2];
    __shared__ int okW[4];

    const int bh = blockIdx.x;             // 0..63 (same-bh blocks share an XCD)
    const int pid = (int)blockIdx.y & 7;   // 0..7
    const int kvHalf = (int)blockIdx.y >> 3;   // 0 = low keys, 1 = high keys
    const int b = bh >> 4;
    const int tid = threadIdx.x;
    const int w = tid >> 6, lane = tid & 63, l31 = lane & 31, lane5 = lane >> 5;

    const size_t qkBase = (size_t)b * SEQ * D_MODEL + (size_t)(bh & 15) * HEAD_DIM;
    const size_t vtBase = (size_t)bh * HEAD_DIM * SEQ;

    // ---- attention_mask is k-loop invariant: scan it once per block ----
    {
        int ok = 1;
        for (int i = tid; i < SEQ; i += 256) ok &= (mask[b * SEQ + i] != 0);
        unsigned long long bal = __ballot(ok != 0);
        if (lane == 0) okW[w] = (bal == ~0ull) ? 1 : 0;
    }
    __syncthreads();
    const int allSeq = okW[0] & okW[1] & okW[2] & okW[3];   // block-uniform

    // per-thread staging constants (chunk c = tid + l*256)
    int stp[2], stcc[2], stj[2];
#pragma unroll
    for (int l = 0; l < 2; ++l) {
        int c = tid + l * 256;
        int p = c >> 3, sl = c & 7;
        stp[l] = p;
        stcc[l] = sl ^ (p & 7);                                   // bank swizzle
        stj[l] = (p & 0x33) | ((p & 4) << 1) | ((p & 8) >> 1);    // swap bits 2,3
    }

    for (int phase = 0; phase < 2; ++phase) {
        const int qt = phase ? pid : 15 - pid;
        const int q0 = qt * 128;
        const int iq = q0 + w * 32 + l31;      // this lane's query row

        const int klo = kvHalf * (qt + 1);     // first k-tile of this half
        const int kend = klo + qt;             // last k-tile (inclusive): qt+1 tiles

        // Q fragments direct from global: B[n=i=l31][k=lane5*8+jj]
        bf16x8 qf[4];
#pragma unroll
        for (int ks = 0; ks < 4; ++ks)
            qf[ks] = *(const bf16x8*)(Q + qkBase + (size_t)iq * D_MODEL + ks * 16 + lane5 * 8);

        float mv = -INFINITY, lv = 0.f;
        f32x16 Ot[2];
#pragma unroll
        for (int dt = 0; dt < 2; ++dt)
#pragma unroll
            for (int e = 0; e < 16; ++e) Ot[dt][e] = 0.f;

        uint4 kreg[2], vreg[2];
        int mreg = 1;
        // prefetch tile klo
#pragma unroll
        for (int l = 0; l < 2; ++l) {
            kreg[l] = *(const uint4*)(K + qkBase + (size_t)(klo * 64 + stj[l]) * D_MODEL + stcc[l] * 8);
            vreg[l] = *(const uint4*)(Vt + vtBase + (size_t)stp[l] * SEQ + klo * 64 + stcc[l] * 8);
        }
        if (!allSeq && tid < 64) mreg = mask[b * SEQ + klo * 64 + tid];

        for (int kt = klo; kt <= kend; ++kt) {
            const int k0 = kt * 64;
            const int buf = kt & 1;
            // ---- stage tile kt into buf (regs -> LDS), prefetch kt+1 ----
#pragma unroll
            for (int l = 0; l < 2; ++l) {
                int c = tid + l * 256;
                *(uint4*)((char*)lds + buf * 8192 + c * 16) = kreg[l];
                *(uint4*)((char*)lds + 16384 + buf * 8192 + c * 16) = vreg[l];
            }
            if (!allSeq && tid < 64) {
                biasS[buf][tid] = mreg ? 0.f : -INFINITY;
                unsigned long long bal = __ballot(mreg != 0);
                if (tid == 0) allokS[buf] = (bal == ~0ull) ? 1 : 0;
            }
            if (kt < kend) {                   // prefetch next tile (overlaps compute)
                const int kn = k0 + 64;
#pragma unroll
                for (int l = 0; l < 2; ++l) {
                    kreg[l] = *(const uint4*)(K + qkBase + (size_t)(kn + stj[l]) * D_MODEL + stcc[l] * 8);
                    vreg[l] = *(const uint4*)(Vt + vtBase + (size_t)stp[l] * SEQ + kn + stcc[l] * 8);
                }
                if (!allSeq && tid < 64) mreg = mask[b * SEQ + kn + tid];
            }
            __syncthreads();                   // buf visible; buf reuse fenced by barrier(kt+1)

            if (64 * kt > q0 + 32 * w + 31) continue;   // wave-uniform: tile above causal diag

            const short* Ks = lds + buf * 4096;
            const short* Vs = lds + 8192 + buf * 4096;

            // wave-uniform active range (diagonal tile triangle)
            const int kHi = q0 + 32 * w + 31 - k0;           // >= 0 here
            const int nT = (kHi >= 32) ? 2 : 1;              // active 32-key QK sub-tiles
            const int nt = ((kHi >> 4) >= 3 ? 3 : (kHi >> 4)) + 1;  // active 16-key PV slots

            // ---- St = K Q^T (up to 8 MFMAs) -----------------------------
            f32x16 St[2];
            __builtin_amdgcn_s_setprio(1);
#pragma unroll
            for (int T = 0; T < 2; ++T) {
                if (T < nT) {
#pragma unroll
                    for (int e = 0; e < 16; ++e) St[T][e] = 0.f;
#pragma unroll
                    for (int ks = 0; ks < 4; ++ks) {
                        int p = T * 32 + l31;
                        int slot = (ks * 2 + lane5) ^ (p & 7);
                        bf16x8 a = *(const bf16x8*)&Ks[p * 64 + slot * 8];
                        St[T] = __builtin_amdgcn_mfma_f32_32x32x16_bf16(a, qf[ks], St[T], 0, 0, 0);
                    }
                }
            }
            __builtin_amdgcn_s_setprio(0);

            // ---- masking ------------------------------------------------
            const bool partial = (k0 + 63 > q0 + 32 * w);
            if (partial) {
#pragma unroll
                for (int T = 0; T < 2; ++T)
                    if (T < nT)
#pragma unroll
                        for (int r = 0; r < 16; ++r) {
                            int j = k0 + 32 * T + 16 * (r >> 3) + 8 * lane5 + (r & 7);
                            if (j > iq) St[T][r] = -INFINITY;
                        }
            }
            if (!allSeq && !allokS[buf]) {
#pragma unroll
                for (int T = 0; T < 2; ++T)
                    if (T < nT)
#pragma unroll
                        for (int r = 0; r < 16; ++r)
                            St[T][r] += biasS[buf][32 * T + 16 * (r >> 3) + 8 * lane5 + (r & 7)];
            }

            // ---- online softmax (defer-max THR=8, per-lane state) -------
            float tm[2];
#pragma unroll
            for (int T = 0; T < 2; ++T) {
                if (T < nT) {
                    float a0 = fmaxf(fmaxf(St[T][0], St[T][1]), fmaxf(St[T][2], St[T][3]));
                    float a1 = fmaxf(fmaxf(St[T][4], St[T][5]), fmaxf(St[T][6], St[T][7]));
                    float a2 = fmaxf(fmaxf(St[T][8], St[T][9]), fmaxf(St[T][10], St[T][11]));
                    float a3 = fmaxf(fmaxf(St[T][12], St[T][13]), fmaxf(St[T][14], St[T][15]));
                    tm[T] = fmaxf(fmaxf(a0, a1), fmaxf(a2, a3));
                } else tm[T] = -INFINITY;
            }
            float rm = fmaxf(tm[0], tm[1]);
            rm = fmaxf(rm, __shfl_xor(rm, 32));
            float mn = fmaxf(mv, rm);
            if (mn > mv + 8.f) {               // rare after warmup (also hits 1st tile)
                float al = exp2f(mv - mn);     // mv=-inf -> 0: correctly zeroes lv/Ot
                lv *= al;
#pragma unroll
                for (int dt = 0; dt < 2; ++dt)
#pragma unroll
                    for (int e = 0; e < 16; ++e) Ot[dt][e] *= al;
                mv = mn;
            }
            // exp2 vs (possibly stale) mv: P bounded by 2^8; -inf scores -> 0
            float rsp[2] = {0.f, 0.f};
#pragma unroll
            for (int T = 0; T < 2; ++T) {
                if (T < nT) {
#pragma unroll
                    for (int r = 0; r < 16; ++r) {
                        float pv = exp2f(St[T][r] - mv);
                        St[T][r] = pv;
                        rsp[T] += pv;
                    }
                }
            }
            float rs = rsp[0] + rsp[1];
            rs += __shfl_xor(rs, 32);
            lv += rs;

            // ---- pack P via v_cvt_pk_bf16_f32 (regs already B-frag order)
            bf16x8 pf[4];
#pragma unroll
            for (int t = 0; t < 4; ++t) {
                if (t < nt) {
                    const int T = t >> 1, hb = t & 1;
                    unsigned u0, u1, u2, u3;
                    asm("v_cvt_pk_bf16_f32 %0, %1, %2" : "=v"(u0)
                        : "v"(St[T][hb * 8 + 0]), "v"(St[T][hb * 8 + 1]));
                    asm("v_cvt_pk_bf16_f32 %0, %1, %2" : "=v"(u1)
                        : "v"(St[T][hb * 8 + 2]), "v"(St[T][hb * 8 + 3]));
                    asm("v_cvt_pk_bf16_f32 %0, %1, %2" : "=v"(u2)
                        : "v"(St[T][hb * 8 + 4]), "v"(St[T][hb * 8 + 5]));
                    asm("v_cvt_pk_bf16_f32 %0, %1, %2" : "=v"(u3)
                        : "v"(St[T][hb * 8 + 6]), "v"(St[T][hb * 8 + 7]));
                    union { unsigned u[4]; bf16x8 v; } pk;
                    pk.u[0] = u0; pk.u[1] = u1; pk.u[2] = u2; pk.u[3] = u3;
                    pf[t] = pk.v;
                }
            }

            // ---- Ot += V^T P^T (up to 8 MFMAs) --------------------------
            __builtin_amdgcn_s_setprio(1);
#pragma unroll
            for (int dt = 0; dt < 2; ++dt)
#pragma unroll
                for (int t = 0; t < 4; ++t) {
                    if (t < nt) {
                        int p = dt * 32 + l31;
                        int slot = (t * 2 + lane5) ^ (p & 7);
                        bf16x8 a = *(const bf16x8*)&Vs[p * 64 + slot * 8];
                        Ot[dt] = __builtin_amdgcn_mfma_f32_32x32x16_bf16(a, pf[t], Ot[dt], 0, 0, 0);
                    }
                }
            __builtin_amdgcn_s_setprio(0);
        }

        // ---- epilogue: store UNNORMALIZED O (bf16) via LDS transpose ----
        __syncthreads();                       // all waves done with K/V buffers
        unsigned short* dst = kvHalf ? P1 : P0;
#pragma unroll
        for (int dt = 0; dt < 2; ++dt)
#pragma unroll
            for (int k = 0; k < 8; ++k) {
                int r0 = 2 * k;
                int d = (r0 & 3) + 4 * lane5 + 8 * (r0 >> 2) + 32 * dt;
                unsigned lo = f2bu(Ot[dt][r0]);
                unsigned hi = f2bu(Ot[dt][r0 + 1]);
                *(unsigned*)&lds[(w * 32 + l31) * 72 + d] = lo | (hi << 16);
            }
        if (lane < 32) {                       // per-row (m, l); rows w*32+l31
            float2 v; v.x = mv; v.y = lv;
            ml[(((size_t)(kvHalf * 4 + b)) * 16 + (bh & 15)) * 2048 + (q0 + w * 32 + l31)] = v;
        }
        __syncthreads();
#pragma unroll
        for (int k = 0; k < 4; ++k) {
            int id = tid + k * 256;
            int r = id >> 3, cc = id & 7;
            uint4 v = *(const uint4*)&lds[r * 72 + cc * 8];
            *(uint4*)(dst + qkBase + (size_t)(q0 + r) * D_MODEL + cc * 8) = v;
        }
        __syncthreads();                       // protect epilogue reads from next phase's staging
    }
}

// ---------------------------------------------------------------------------
// Combine the two KV-halves in-place on CTX (= P0):
//   O = (O0*e2(m0-m) + O1*e2(m1-m)) / (l0*e2(m0-m) + l1*e2(m1-m)), m=max.
// Elementwise, 8 bf16 per thread; f0/f1 uniform per (row, head).
// ---------------------------------------------------------------------------
__global__ __launch_bounds__(256) void flash_combine(unsigned short* __restrict__ CTX,
                                                     const unsigned short* __restrict__ P1,
                                                     const float2* __restrict__ ml) {
    size_t i8 = (size_t)blockIdx.x * 256 + threadIdx.x;   // 1,048,576 total
    size_t e = i8 * 8;
    int row = (int)(e >> 10);          // global row 0..8191
    int col = (int)(e & 1023);
    int head = col >> 6;
    int b = row >> 11, s = row & 2047;

    float2 a0 = ml[(((size_t)b) * 16 + head) * 2048 + s];
    float2 a1 = ml[(((size_t)(4 + b)) * 16 + head) * 2048 + s];
    float m = fmaxf(a0.x, a1.x);
    float f0 = exp2f(a0.x - m);        // m0=-inf impossible (low half has kt=0)
    float f1 = exp2f(a1.x - m);        // m1=-inf -> 0 (empty high half)
    float l = a0.y * f0 + a1.y * f1;
    float inv = 1.f / l;
    f0 *= inv; f1 *= inv;

    uint4 u0 = *(const uint4*)(CTX + e);
    uint4 u1 = *(const uint4*)(P1 + e);
    unsigned o[4];
    unsigned uu0[4] = {u0.x, u0.y, u0.z, u0.w};
    unsigned uu1[4] = {u1.x, u1.y, u1.z, u1.w};
#pragma unroll
    for (int j = 0; j < 4; ++j) {
        float xl = bu2f(uu0[j] << 16) * f0 + bu2f(uu1[j] << 16) * f1;
        float xh = bu2f(uu0[j] & 0xFFFF0000u) * f0 + bu2f(uu1[j] & 0xFFFF0000u) * f1;
        o[j] = f2bu(xl) | ((unsigned)f2bu(xh) << 16);
    }
    uint4 ov; ov.x = o[0]; ov.y = o[1]; ov.z = o[2]; ov.w = o[3];
    *(uint4*)(CTX + e) = ov;
}

// ---------------------------------------------------------------------------
extern "C" void kernel_launch(void* const* d_in, const int* in_sizes, int n_in,
                              void* d_out, int out_size, void* d_ws, size_t ws_size,
                              hipStream_t stream) {
    const float* x  = (const float*)d_in[0];
    const int* mask = (const int*)d_in[1];
    const float* wq = (const float*)d_in[2];
    const float* wk = (const float*)d_in[3];
    const float* wv = (const float*)d_in[4];
    const float* wo = (const float*)d_in[5];
    float* out = (float*)d_out;

    const size_t NE = (size_t)M_TOTAL * D_MODEL;
    const size_t WE = (size_t)D_MODEL * D_MODEL;
    unsigned short* ws  = (unsigned short*)d_ws;
    unsigned short* xb  = ws;            // dead after qkv_gemm -> P1 partial buffer
    unsigned short* wqb = xb + NE;       // dead after qkv_gemm -> ml buffer (2 MB exact)
    unsigned short* wkb = wqb + WE;
    unsigned short* wvb = wkb + WE;
    unsigned short* wob = wvb + WE;
    unsigned short* Qb  = wob + WE;
    unsigned short* Kb  = Qb + NE;
    unsigned short* Vtb = Kb + NE;
    unsigned short* CTX = Vtb + NE;      // half-0 partial, then combined in-place

    cast_all<<<(int)((NE + 4 * WE) / 4 / 256), 256, 0, stream>>>(x, wq, wk, wv, wo, ws);

    qkv_gemm<<<dim3(24, M_TOTAL / 128), 256, 0, stream>>>(xb, wqb, wkb, wvb, Qb, Kb, Vtb);

    flash32<<<dim3(64, 16), 256, 0, stream>>>(Qb, Kb, Vtb, mask, CTX, xb, (float2*)wqb);

    flash_combine<<<(int)(NE / 8 / 256), 256, 0, stream>>>(CTX, xb, (const float2*)wqb);

    out_gemm<<<dim3(D_MODEL / 128, M_TOTAL / 128), 256, 0, stream>>>(CTX, wob, out);
}

// Round 11
// 307.795 us; speedup vs baseline: 1.2805x; 1.0780x over previous
//
#include <hip/hip_runtime.h>
#include <cstdint>
#include <cstddef>

#define D_MODEL 1024
#define N_HEADS 16
#define HEAD_DIM 64
#define BATCH 4
#define SEQ 2048
#define M_TOTAL (BATCH * SEQ)   // 8192

typedef __attribute__((ext_vector_type(8))) short bf16x8;    // 8 bf16 = 4 VGPRs
typedef __attribute__((ext_vector_type(4))) float f32x4;
typedef __attribute__((ext_vector_type(16))) float f32x16;

// scale = 1/sqrt(64) * log2(e), folded into Q projection (softmax in exp2 domain)
#define Q_SCALE 0.18033688011112042f

__device__ __forceinline__ unsigned short f2bu(float f) {   // RNE
    union { float f; unsigned u; } x; x.f = f;
    unsigned r = x.u + 0x7FFFu + ((x.u >> 16) & 1u);
    return (unsigned short)(r >> 16);
}

__device__ __forceinline__ void async16(void* lds, const void* g) {
    __builtin_amdgcn_global_load_lds(
        (const __attribute__((address_space(1))) void*)g,
        (__attribute__((address_space(3))) void*)lds, 16, 0, 0);
}

// ---------------------------------------------------------------------------
// One fused fp32 -> bf16 cast for x + 4 weights (contiguous dst in ws).
// ---------------------------------------------------------------------------
__global__ __launch_bounds__(256) void cast_all(const float* __restrict__ x,
                                                const float* __restrict__ wq,
                                                const float* __restrict__ wk,
                                                const float* __restrict__ wv,
                                                const float* __restrict__ wo,
                                                unsigned short* __restrict__ dst) {
    const size_t NE = (size_t)M_TOTAL * D_MODEL;
    const size_t WE = (size_t)D_MODEL * D_MODEL;
    size_t i4 = (size_t)blockIdx.x * 256 + threadIdx.x;
    size_t e = i4 * 4;
    const float* src; size_t off;
    if (e < NE) { src = x; off = e; }
    else {
        size_t t = e - NE;
        int r = (int)(t / WE); off = t - (size_t)r * WE;
        src = (r == 0) ? wq : (r == 1) ? wk : (r == 2) ? wv : wo;
    }
    float4 v = *(const float4*)(src + off);
    ushort4 o;
    o.x = f2bu(v.x); o.y = f2bu(v.y); o.z = f2bu(v.z); o.w = f2bu(v.w);
    ((ushort4*)dst)[i4] = o;
}

// ---------------------------------------------------------------------------
// Fused Q/K/V projection, 8-PHASE 256x256 tile (T3+T4 port, guide m201):
//   * BM=BN=256, BK=64, 512 threads = 8 waves (2M x 4N), per-wave C 128x64,
//     acc[8][4] f32x4 (128 VGPR).
//   * LDS 128KB: ring of 4 half-tile buffers per operand (16KB each:
//     256 rows x 32 k). Half-tile H_j (j = 2*kt + s) lives in ring slot j&3.
//   * Per K-tile, 4 phases: {issue 2 global_load_lds of a freed half-slot;
//     ds_read frags; barrier; 16 MFMA (setprio); barrier}. Counted
//     s_waitcnt vmcnt(8) ONLY at phase-1/phase-3 ends (tail: 4 -> 0) --
//     loads stay in flight across barriers (T4; never vmcnt(0) mid-loop).
//   * Issue schedule: tile kt issues H_{2kt+3} (A ph0, B ph1) and
//     H_{2kt+4} (A ph2, B ph3). In-order vmcnt => vmcnt(8) at ph1-end
//     guarantees H_{2kt+1} landed; at ph3-end guarantees H_{2kt+2}.
//     Write-after-read: H_{2kt+3}'s slot freed by tile kt-1 ph3 barrier;
//     H_{2kt+4}'s slot freed by this tile's ph1-end barrier.
//   * Swizzle: chunk ^= ((row>>1)&3) involution on the 4 16B-chunks per
//     32-k row (session-proven; 2-way bank alias = free). LDS dest linear.
//   * Grid 384 blocks XCD-clustered: each XCD owns 4 A row-panels.
// ---------------------------------------------------------------------------
__device__ __forceinline__ void stageHalfA(const unsigned short* __restrict__ src,
                                           int srcRowBase, int j, int tid,
                                           const int* gp, const int* gcc, short* lds) {
    if (j >= 32) return;
#pragma unroll
    for (int l = 0; l < 2; ++l)
        async16((char*)lds + ((j & 3) << 14) + (tid + l * 512) * 16,
                src + (size_t)(srcRowBase + gp[l]) * 1024 + j * 32 + gcc[l] * 8);
}
__device__ __forceinline__ void stageHalfB(const unsigned short* __restrict__ src,
                                           int srcRowBase, int j, int tid,
                                           const int* gp, const int* gcc, short* lds) {
    if (j >= 32) return;
#pragma unroll
    for (int l = 0; l < 2; ++l)
        async16((char*)lds + 65536 + ((j & 3) << 14) + (tid + l * 512) * 16,
                src + (size_t)(srcRowBase + gp[l]) * 1024 + j * 32 + gcc[l] * 8);
}

__global__ __launch_bounds__(512) void qkv256(const unsigned short* __restrict__ X,
                                              const unsigned short* __restrict__ W0,
                                              const unsigned short* __restrict__ W1,
                                              const unsigned short* __restrict__ W2,
                                              unsigned short* __restrict__ Y0,
                                              unsigned short* __restrict__ Y1,
                                              unsigned short* __restrict__ Vt) {
    __shared__ short lds[65536];           // A ring 4x8192 shorts @0, B ring @32768

    const int id = (int)blockIdx.x;        // 0..383
    const int xcd = id & 7, slot = id >> 3;        // 48 slots/xcd
    const int ty = xcd * 4 + slot / 12;            // A row-tile 0..31 (XCD-local)
    const int r12 = slot % 12;
    const int sel = r12 >> 2;                      // 0..2
    const int tx = r12 & 3;                        // 0..3
    const unsigned short* W = (sel == 0) ? W0 : (sel == 1) ? W1 : W2;
    const float scl = (sel == 0) ? Q_SCALE : 1.0f;
    const int rowBase = ty * 256;
    const int colBase = tx * 256;

    const int tid = threadIdx.x;
    const int wid = tid >> 6, lane = tid & 63, quad = lane >> 4, l15 = lane & 15;
    const int wm = wid >> 2, wn = wid & 3;

    // staging constants: chunk g = tid + l*512; row p = g>>2, slot sl = g&3,
    // source chunk cc = sl ^ ((p>>1)&3)  (involution; read undoes it)
    int gp[2], gcc[2];
#pragma unroll
    for (int l = 0; l < 2; ++l) {
        int g = tid + l * 512;
        gp[l] = g >> 2;
        gcc[l] = (g & 3) ^ ((gp[l] >> 1) & 3);
    }

    f32x4 acc[8][4];
#pragma unroll
    for (int mi = 0; mi < 8; ++mi)
#pragma unroll
        for (int ni = 0; ni < 4; ++ni)
#pragma unroll
            for (int e = 0; e < 4; ++e) acc[mi][ni][e] = 0.f;

    // ---- prologue: issue H0, H1, H2 (A+B each); wait for H0; barrier ----
    stageHalfA(X, rowBase, 0, tid, gp, gcc, lds);
    stageHalfB(W, colBase, 0, tid, gp, gcc, lds);
    stageHalfA(X, rowBase, 1, tid, gp, gcc, lds);
    stageHalfB(W, colBase, 1, tid, gp, gcc, lds);
    stageHalfA(X, rowBase, 2, tid, gp, gcc, lds);
    stageHalfB(W, colBase, 2, tid, gp, gcc, lds);
    asm volatile("s_waitcnt vmcnt(8)" ::: "memory");
    __builtin_amdgcn_s_barrier();

    for (int kt = 0; kt < 16; ++kt) {
        const int qA = (2 * kt) & 3;       // ring slot: k-half 0 of tile kt
        const int qB = (2 * kt + 1) & 3;   // ring slot: k-half 1
        bf16x8 afr[4], bfr[4];

        // ================= phase 0: s=0, mi 0..3 (+ B s0 frags) ==========
        stageHalfA(X, rowBase, 2 * kt + 3, tid, gp, gcc, lds);
#pragma unroll
        for (int ni = 0; ni < 4; ++ni) {
            int rb = wn * 64 + ni * 16 + l15;
            int sl = quad ^ ((rb >> 1) & 3);
            bfr[ni] = *(const bf16x8*)&lds[32768 + qA * 8192 + rb * 32 + sl * 8];
        }
#pragma unroll
        for (int i = 0; i < 4; ++i) {
            int r = wm * 128 + i * 16 + l15;
            int sl = quad ^ ((r >> 1) & 3);
            afr[i] = *(const bf16x8*)&lds[qA * 8192 + r * 32 + sl * 8];
        }
        __builtin_amdgcn_s_barrier();
        __builtin_amdgcn_s_setprio(1);
#pragma unroll
        for (int i = 0; i < 4; ++i)
#pragma unroll
            for (int ni = 0; ni < 4; ++ni)
                acc[i][ni] = __builtin_amdgcn_mfma_f32_16x16x32_bf16(afr[i], bfr[ni], acc[i][ni], 0, 0, 0);
        __builtin_amdgcn_s_setprio(0);
        __builtin_amdgcn_s_barrier();

        // ================= phase 1: s=0, mi 4..7 =========================
        stageHalfB(W, colBase, 2 * kt + 3, tid, gp, gcc, lds);
#pragma unroll
        for (int i = 0; i < 4; ++i) {
            int r = wm * 128 + (4 + i) * 16 + l15;
            int sl = quad ^ ((r >> 1) & 3);
            afr[i] = *(const bf16x8*)&lds[qA * 8192 + r * 32 + sl * 8];
        }
        __builtin_amdgcn_s_barrier();
        __builtin_amdgcn_s_setprio(1);
#pragma unroll
        for (int i = 0; i < 4; ++i)
#pragma unroll
            for (int ni = 0; ni < 4; ++ni)
                acc[4 + i][ni] = __builtin_amdgcn_mfma_f32_16x16x32_bf16(afr[i], bfr[ni], acc[4 + i][ni], 0, 0, 0);
        __builtin_amdgcn_s_setprio(0);
        if (kt < 15) { asm volatile("s_waitcnt vmcnt(8)" ::: "memory"); }
        else         { asm volatile("s_waitcnt vmcnt(0)" ::: "memory"); }
        __builtin_amdgcn_s_barrier();      // H_{2kt+1} now visible to all waves

        // ================= phase 2: s=1, mi 0..3 (+ B s1 frags) ==========
        stageHalfA(X, rowBase, 2 * kt + 4, tid, gp, gcc, lds);
#pragma unroll
        for (int ni = 0; ni < 4; ++ni) {
            int rb = wn * 64 + ni * 16 + l15;
            int sl = quad ^ ((rb >> 1) & 3);
            bfr[ni] = *(const bf16x8*)&lds[32768 + qB * 8192 + rb * 32 + sl * 8];
        }
#pragma unroll
        for (int i = 0; i < 4; ++i) {
            int r = wm * 128 + i * 16 + l15;
            int sl = quad ^ ((r >> 1) & 3);
            afr[i] = *(const bf16x8*)&lds[qB * 8192 + r * 32 + sl * 8];
        }
        __builtin_amdgcn_s_barrier();
        __builtin_amdgcn_s_setprio(1);
#pragma unroll
        for (int i = 0; i < 4; ++i)
#pragma unroll
            for (int ni = 0; ni < 4; ++ni)
                acc[i][ni] = __builtin_amdgcn_mfma_f32_16x16x32_bf16(afr[i], bfr[ni], acc[i][ni], 0, 0, 0);
        __builtin_amdgcn_s_setprio(0);
        __builtin_amdgcn_s_barrier();

        // ================= phase 3: s=1, mi 4..7 =========================
        stageHalfB(W, colBase, 2 * kt + 4, tid, gp, gcc, lds);
#pragma unroll
        for (int i = 0; i < 4; ++i) {
            int r = wm * 128 + (4 + i) * 16 + l15;
            int sl = quad ^ ((r >> 1) & 3);
            afr[i] = *(const bf16x8*)&lds[qB * 8192 + r * 32 + sl * 8];
        }
        __builtin_amdgcn_s_barrier();
        __builtin_amdgcn_s_setprio(1);
#pragma unroll
        for (int i = 0; i < 4; ++i)
#pragma unroll
            for (int ni = 0; ni < 4; ++ni)
                acc[4 + i][ni] = __builtin_amdgcn_mfma_f32_16x16x32_bf16(afr[i], bfr[ni], acc[4 + i][ni], 0, 0, 0);
        __builtin_amdgcn_s_setprio(0);
        if (kt < 14)      { asm volatile("s_waitcnt vmcnt(8)" ::: "memory"); }
        else if (kt == 14){ asm volatile("s_waitcnt vmcnt(4)" ::: "memory"); }
        // kt==15: no wait needed (no further LDS reads)
        __builtin_amdgcn_s_barrier();      // H_{2kt+2} now visible to all waves
    }

    // ---- epilogue: write C -------------------------------------------------
    if (sel != 2) {
        unsigned short* Y = (sel == 0) ? Y0 : Y1;
#pragma unroll
        for (int mi = 0; mi < 8; ++mi)
#pragma unroll
            for (int ni = 0; ni < 4; ++ni)
#pragma unroll
                for (int reg = 0; reg < 4; ++reg) {
                    int row = rowBase + wm * 128 + mi * 16 + quad * 4 + reg;
                    int col = colBase + wn * 64 + ni * 16 + l15;
                    Y[(size_t)row * 1024 + col] = f2bu(acc[mi][ni][reg] * scl);
                }
    } else {
        // transposed V write: Vt[((b*16+h)*64+d)*SEQ + s], 4 consecutive s per store
#pragma unroll
        for (int mi = 0; mi < 8; ++mi) {
            int row0 = rowBase + wm * 128 + mi * 16 + quad * 4;   // reg 0 row
            int bb = row0 >> 11;
            int s0 = row0 & 2047;
#pragma unroll
            for (int ni = 0; ni < 4; ++ni) {
                int col = colBase + wn * 64 + ni * 16 + l15;
                int hh = col >> 6, dd = col & 63;
                ushort4 pk;
                pk.x = f2bu(acc[mi][ni][0]); pk.y = f2bu(acc[mi][ni][1]);
                pk.z = f2bu(acc[mi][ni][2]); pk.w = f2bu(acc[mi][ni][3]);
                *(ushort4*)(Vt + (((size_t)bb * 16 + hh) * 64 + dd) * SEQ + s0) = pk;
            }
        }
    }
}

// ---------------------------------------------------------------------------
// Output projection (r8 version, T1 XCD remap, PASSED).
// ---------------------------------------------------------------------------
__global__ __launch_bounds__(256) void out_gemm(const unsigned short* __restrict__ X,
                                                const unsigned short* __restrict__ W,
                                                float* __restrict__ Y) {
    __shared__ short As[128 * 32];
    __shared__ short Bs[128 * 32];

    const int id = (int)blockIdx.x + 8 * (int)blockIdx.y;
    const int xcd = id & 7, slot = id >> 3;
    const int ty = xcd * 8 + (slot >> 3);
    const int tx = slot & 7;

    const int tid = threadIdx.x;
    const int w = tid >> 6, lane = tid & 63, quad = lane >> 4, l15 = lane & 15;
    const int wm = w & 1, wn = w >> 1;
    const int rowBase = ty * 128;
    const int colBase = tx * 128;

    f32x4 acc[4][4];
#pragma unroll
    for (int mi = 0; mi < 4; ++mi)
#pragma unroll
        for (int ni = 0; ni < 4; ++ni)
#pragma unroll
            for (int e = 0; e < 4; ++e) acc[mi][ni][e] = 0.f;

    for (int k0 = 0; k0 < 1024; k0 += 32) {
        __syncthreads();
#pragma unroll
        for (int l = 0; l < 2; ++l) {
            int c = tid + l * 256;
            int row = c >> 2, ccs = c & 3;
            int cc = ccs ^ ((row >> 1) & 3);
            async16((char*)As + c * 16, X + (size_t)(rowBase + row) * 1024 + k0 + cc * 8);
            async16((char*)Bs + c * 16, W + (size_t)(colBase + row) * 1024 + k0 + cc * 8);
        }
        __syncthreads();

        bf16x8 a[4], b[4];
#pragma unroll
        for (int mi = 0; mi < 4; ++mi) {
            int r = wm * 64 + mi * 16 + l15;
            int slt = quad ^ ((r >> 1) & 3);
            a[mi] = *(const bf16x8*)&As[r * 32 + slt * 8];
        }
#pragma unroll
        for (int ni = 0; ni < 4; ++ni) {
            int r = wn * 64 + ni * 16 + l15;
            int slt = quad ^ ((r >> 1) & 3);
            b[ni] = *(const bf16x8*)&Bs[r * 32 + slt * 8];
        }
#pragma unroll
        for (int mi = 0; mi < 4; ++mi)
#pragma unroll
            for (int ni = 0; ni < 4; ++ni)
                acc[mi][ni] = __builtin_amdgcn_mfma_f32_16x16x32_bf16(a[mi], b[ni], acc[mi][ni], 0, 0, 0);
    }

#pragma unroll
    for (int mi = 0; mi < 4; ++mi)
#pragma unroll
        for (int ni = 0; ni < 4; ++ni)
#pragma unroll
            for (int reg = 0; reg < 4; ++reg) {
                int row = rowBase + wm * 64 + mi * 16 + quad * 4 + reg;
                int col = colBase + wn * 64 + ni * 16 + l15;
                Y[(size_t)row * 1024 + col] = acc[mi][ni][reg];
            }
}

// ---------------------------------------------------------------------------
// Flash attention — byte-identical to rounds 5/8 (PASSED, ~126 us):
//   KVBLK=64, St[2], paired q-tiles {15-pid,pid} (36 iters, perfect balance),
//   XCD-local grid (64,8), double-buffered K/V with ONE barrier per tile,
//   wave-uniform triangle guards, defer-max THR=8, v_cvt_pk pack,
//   allSeq fast path, setprio around MFMA clusters.
// (Dead ends, do not retry: V-direct-from-global [r6/r7 absmax 6.08];
//  KV-split occupancy [r9/r10: unified VGPR>128 caps 2 blocks/CU].)
// ---------------------------------------------------------------------------
__global__ __launch_bounds__(256) void flash32(const unsigned short* __restrict__ Q,
                                               const unsigned short* __restrict__ K,
                                               const unsigned short* __restrict__ Vt,
                                               const int* __restrict__ mask,
                                               unsigned short* __restrict__ CTX) {
    __shared__ short lds[16384];           // K dbuf [0..8191], V dbuf [8192..16383] (shorts)
    __shared__ float biasS[2][64];
    __shared__ int allokS[2];
    __shared__ int okW[4];

    const int bh = blockIdx.x;             // 0..63 (same-bh blocks share an XCD)
    const int pid = blockIdx.y;            // 0..7
    const int b = bh >> 4;
    const int tid = threadIdx.x;
    const int w = tid >> 6, lane = tid & 63, l31 = lane & 31, lane5 = lane >> 5;

    const size_t qkBase = (size_t)b * SEQ * D_MODEL + (size_t)(bh & 15) * HEAD_DIM;
    const size_t vtBase = (size_t)bh * HEAD_DIM * SEQ;

    // ---- attention_mask is k-loop invariant: scan it once per block ----
    {
        int ok = 1;
        for (int i = tid; i < SEQ; i += 256) ok &= (mask[b * SEQ + i] != 0);
        unsigned long long bal = __ballot(ok != 0);
        if (lane == 0) okW[w] = (bal == ~0ull) ? 1 : 0;
    }
    __syncthreads();
    const int allSeq = okW[0] & okW[1] & okW[2] & okW[3];   // block-uniform

    // per-thread staging constants (chunk c = tid + l*256)
    int stp[2], stcc[2], stj[2];
#pragma unroll
    for (int l = 0; l < 2; ++l) {
        int c = tid + l * 256;
        int p = c >> 3, sl = c & 7;
        stp[l] = p;
        stcc[l] = sl ^ (p & 7);                                   // bank swizzle
        stj[l] = (p & 0x33) | ((p & 4) << 1) | ((p & 8) >> 1);    // swap bits 2,3
    }

    for (int phase = 0; phase < 2; ++phase) {
        const int qt = phase ? pid : 15 - pid;
        const int q0 = qt * 128;
        const int iq = q0 + w * 32 + l31;      // this lane's query row

        // Q fragments direct from global: B[n=i=l31][k=lane5*8+jj]
        bf16x8 qf[4];
#pragma unroll
        for (int ks = 0; ks < 4; ++ks)
            qf[ks] = *(const bf16x8*)(Q + qkBase + (size_t)iq * D_MODEL + ks * 16 + lane5 * 8);

        float mv = -INFINITY, lv = 0.f;
        f32x16 Ot[2];
#pragma unroll
        for (int dt = 0; dt < 2; ++dt)
#pragma unroll
            for (int e = 0; e < 16; ++e) Ot[dt][e] = 0.f;

        const int ktmax = 2 * qt + 1;

        uint4 kreg[2], vreg[2];
        int mreg = 1;
        // prefetch tile 0
#pragma unroll
        for (int l = 0; l < 2; ++l) {
            kreg[l] = *(const uint4*)(K + qkBase + (size_t)stj[l] * D_MODEL + stcc[l] * 8);
            vreg[l] = *(const uint4*)(Vt + vtBase + (size_t)stp[l] * SEQ + stcc[l] * 8);
        }
        if (!allSeq && tid < 64) mreg = mask[b * SEQ + tid];

        for (int kt = 0; kt <= ktmax; ++kt) {
            const int k0 = kt * 64;
            const int buf = kt & 1;
            // ---- stage tile kt into buf (regs -> LDS), prefetch kt+1 ----
#pragma unroll
            for (int l = 0; l < 2; ++l) {
                int c = tid + l * 256;
                *(uint4*)((char*)lds + buf * 8192 + c * 16) = kreg[l];
                *(uint4*)((char*)lds + 16384 + buf * 8192 + c * 16) = vreg[l];
            }
            if (!allSeq && tid < 64) {
                biasS[buf][tid] = mreg ? 0.f : -INFINITY;
                unsigned long long bal = __ballot(mreg != 0);
                if (tid == 0) allokS[buf] = (bal == ~0ull) ? 1 : 0;
            }
            if (kt < ktmax) {                  // prefetch next tile (overlaps compute)
                const int kn = k0 + 64;
#pragma unroll
                for (int l = 0; l < 2; ++l) {
                    kreg[l] = *(const uint4*)(K + qkBase + (size_t)(kn + stj[l]) * D_MODEL + stcc[l] * 8);
                    vreg[l] = *(const uint4*)(Vt + vtBase + (size_t)stp[l] * SEQ + kn + stcc[l] * 8);
                }
                if (!allSeq && tid < 64) mreg = mask[b * SEQ + kn + tid];
            }
            __syncthreads();                   // buf visible; buf reuse fenced by barrier(kt+1)

            if (64 * kt > q0 + 32 * w + 31) continue;   // wave-uniform: tile above causal diag

            const short* Ks = lds + buf * 4096;
            const short* Vs = lds + 8192 + buf * 4096;

            // wave-uniform active range (diagonal tile triangle)
            const int kHi = q0 + 32 * w + 31 - k0;           // >= 0 here
            const int nT = (kHi >= 32) ? 2 : 1;              // active 32-key QK sub-tiles
            const int nt = ((kHi >> 4) >= 3 ? 3 : (kHi >> 4)) + 1;  // active 16-key PV slots

            // ---- St = K Q^T (up to 8 MFMAs) -----------------------------
            f32x16 St[2];
            __builtin_amdgcn_s_setprio(1);
#pragma unroll
            for (int T = 0; T < 2; ++T) {
                if (T < nT) {
#pragma unroll
                    for (int e = 0; e < 16; ++e) St[T][e] = 0.f;
#pragma unroll
                    for (int ks = 0; ks < 4; ++ks) {
                        int p = T * 32 + l31;
                        int slot = (ks * 2 + lane5) ^ (p & 7);
                        bf16x8 a = *(const bf16x8*)&Ks[p * 64 + slot * 8];
                        St[T] = __builtin_amdgcn_mfma_f32_32x32x16_bf16(a, qf[ks], St[T], 0, 0, 0);
                    }
                }
            }
            __builtin_amdgcn_s_setprio(0);

            // ---- masking ------------------------------------------------
            const bool partial = (k0 + 63 > q0 + 32 * w);
            if (partial) {
#pragma unroll
                for (int T = 0; T < 2; ++T)
                    if (T < nT)
#pragma unroll
                        for (int r = 0; r < 16; ++r) {
                            int j = k0 + 32 * T + 16 * (r >> 3) + 8 * lane5 + (r & 7);
                            if (j > iq) St[T][r] = -INFINITY;
                        }
            }
            if (!allSeq && !allokS[buf]) {
#pragma unroll
                for (int T = 0; T < 2; ++T)
                    if (T < nT)
#pragma unroll
                        for (int r = 0; r < 16; ++r)
                            St[T][r] += biasS[buf][32 * T + 16 * (r >> 3) + 8 * lane5 + (r & 7)];
            }

            // ---- online softmax (defer-max THR=8, per-lane state) -------
            float tm[2];
#pragma unroll
            for (int T = 0; T < 2; ++T) {
                if (T < nT) {
                    float a0 = fmaxf(fmaxf(St[T][0], St[T][1]), fmaxf(St[T][2], St[T][3]));
                    float a1 = fmaxf(fmaxf(St[T][4], St[T][5]), fmaxf(St[T][6], St[T][7]));
                    float a2 = fmaxf(fmaxf(St[T][8], St[T][9]), fmaxf(St[T][10], St[T][11]));
                    float a3 = fmaxf(fmaxf(St[T][12], St[T][13]), fmaxf(St[T][14], St[T][15]));
                    tm[T] = fmaxf(fmaxf(a0, a1), fmaxf(a2, a3));
                } else tm[T] = -INFINITY;
            }
            float rm = fmaxf(tm[0], tm[1]);
            rm = fmaxf(rm, __shfl_xor(rm, 32));
            float mn = fmaxf(mv, rm);
            if (mn > mv + 8.f) {               // rare after warmup (also hits 1st tile)
                float al = exp2f(mv - mn);     // mv=-inf -> 0: correctly zeroes lv/Ot
                lv *= al;
#pragma unroll
                for (int dt = 0; dt < 2; ++dt)
#pragma unroll
                    for (int e = 0; e < 16; ++e) Ot[dt][e] *= al;
                mv = mn;
            }
            // exp2 vs (possibly stale) mv: P bounded by 2^8; -inf scores -> 0
            float rsp[2] = {0.f, 0.f};
#pragma unroll
            for (int T = 0; T < 2; ++T) {
                if (T < nT) {
#pragma unroll
                    for (int r = 0; r < 16; ++r) {
                        float pv = exp2f(St[T][r] - mv);
                        St[T][r] = pv;
                        rsp[T] += pv;
                    }
                }
            }
            float rs = rsp[0] + rsp[1];
            rs += __shfl_xor(rs, 32);
            lv += rs;

            // ---- pack P via v_cvt_pk_bf16_f32 (regs already B-frag order)
            bf16x8 pf[4];
#pragma unroll
            for (int t = 0; t < 4; ++t) {
                if (t < nt) {
                    const int T = t >> 1, hb = t & 1;
                    unsigned u0, u1, u2, u3;
                    asm("v_cvt_pk_bf16_f32 %0, %1, %2" : "=v"(u0)
                        : "v"(St[T][hb * 8 + 0]), "v"(St[T][hb * 8 + 1]));
                    asm("v_cvt_pk_bf16_f32 %0, %1, %2" : "=v"(u1)
                        : "v"(St[T][hb * 8 + 2]), "v"(St[T][hb * 8 + 3]));
                    asm("v_cvt_pk_bf16_f32 %0, %1, %2" : "=v"(u2)
                        : "v"(St[T][hb * 8 + 4]), "v"(St[T][hb * 8 + 5]));
                    asm("v_cvt_pk_bf16_f32 %0, %1, %2" : "=v"(u3)
                        : "v"(St[T][hb * 8 + 6]), "v"(St[T][hb * 8 + 7]));
                    union { unsigned u[4]; bf16x8 v; } pk;
                    pk.u[0] = u0; pk.u[1] = u1; pk.u[2] = u2; pk.u[3] = u3;
                    pf[t] = pk.v;
                }
            }

            // ---- Ot += V^T P^T (up to 8 MFMAs) --------------------------
            __builtin_amdgcn_s_setprio(1);
#pragma unroll
            for (int dt = 0; dt < 2; ++dt)
#pragma unroll
                for (int t = 0; t < 4; ++t) {
                    if (t < nt) {
                        int p = dt * 32 + l31;
                        int slot = (t * 2 + lane5) ^ (p & 7);
                        bf16x8 a = *(const bf16x8*)&Vs[p * 64 + slot * 8];
                        Ot[dt] = __builtin_amdgcn_mfma_f32_32x32x16_bf16(a, pf[t], Ot[dt], 0, 0, 0);
                    }
                }
            __builtin_amdgcn_s_setprio(0);
        }

        // ---- epilogue: normalize, transpose via LDS, coalesced store ----
        __syncthreads();                       // all waves done with K/V buffers
        const float inv = 1.f / lv;
#pragma unroll
        for (int dt = 0; dt < 2; ++dt)
#pragma unroll
            for (int k = 0; k < 8; ++k) {
                int r0 = 2 * k;
                int d = (r0 & 3) + 4 * lane5 + 8 * (r0 >> 2) + 32 * dt;
                unsigned lo = f2bu(Ot[dt][r0] * inv);
                unsigned hi = f2bu(Ot[dt][r0 + 1] * inv);
                *(unsigned*)&lds[(w * 32 + l31) * 72 + d] = lo | (hi << 16);
            }
        __syncthreads();
#pragma unroll
        for (int k = 0; k < 4; ++k) {
            int id = tid + k * 256;
            int r = id >> 3, cc = id & 7;
            uint4 v = *(const uint4*)&lds[r * 72 + cc * 8];
            *(uint4*)(CTX + qkBase + (size_t)(q0 + r) * D_MODEL + cc * 8) = v;
        }
        __syncthreads();                       // protect epilogue reads from next phase's staging
    }
}

// ---------------------------------------------------------------------------
extern "C" void kernel_launch(void* const* d_in, const int* in_sizes, int n_in,
                              void* d_out, int out_size, void* d_ws, size_t ws_size,
                              hipStream_t stream) {
    const float* x  = (const float*)d_in[0];
    const int* mask = (const int*)d_in[1];
    const float* wq = (const float*)d_in[2];
    const float* wk = (const float*)d_in[3];
    const float* wv = (const float*)d_in[4];
    const float* wo = (const float*)d_in[5];
    float* out = (float*)d_out;

    const size_t NE = (size_t)M_TOTAL * D_MODEL;
    const size_t WE = (size_t)D_MODEL * D_MODEL;
    unsigned short* ws  = (unsigned short*)d_ws;
    unsigned short* xb  = ws;
    unsigned short* wqb = xb + NE;
    unsigned short* wkb = wqb + WE;
    unsigned short* wvb = wkb + WE;
    unsigned short* wob = wvb + WE;
    unsigned short* Qb  = wob + WE;
    unsigned short* Kb  = Qb + NE;
    unsigned short* Vtb = Kb + NE;
    unsigned short* CTX = Vtb + NE;

    cast_all<<<(int)((NE + 4 * WE) / 4 / 256), 256, 0, stream>>>(x, wq, wk, wv, wo, ws);

    qkv256<<<dim3(384), 512, 0, stream>>>(xb, wqb, wkb, wvb, Qb, Kb, Vtb);

    flash32<<<dim3(64, 8), 256, 0, stream>>>(Qb, Kb, Vtb, mask, CTX);

    out_gemm<<<dim3(D_MODEL / 128, M_TOTAL / 128), 256, 0, stream>>>(CTX, wob, out);
}

// Round 12
// 306.443 us; speedup vs baseline: 1.2862x; 1.0044x over previous
//
#include <hip/hip_runtime.h>
#include <cstdint>
#include <cstddef>

#define D_MODEL 1024
#define N_HEADS 16
#define HEAD_DIM 64
#define BATCH 4
#define SEQ 2048
#define M_TOTAL (BATCH * SEQ)   // 8192

typedef __attribute__((ext_vector_type(8))) short bf16x8;    // 8 bf16 = 4 VGPRs
typedef __attribute__((ext_vector_type(4))) float f32x4;
typedef __attribute__((ext_vector_type(16))) float f32x16;

// scale = 1/sqrt(64) * log2(e), folded into Q projection (softmax in exp2 domain)
#define Q_SCALE 0.18033688011112042f

__device__ __forceinline__ unsigned short f2bu(float f) {   // RNE
    union { float f; unsigned u; } x; x.f = f;
    unsigned r = x.u + 0x7FFFu + ((x.u >> 16) & 1u);
    return (unsigned short)(r >> 16);
}

__device__ __forceinline__ void async16(void* lds, const void* g) {
    __builtin_amdgcn_global_load_lds(
        (const __attribute__((address_space(1))) void*)g,
        (__attribute__((address_space(3))) void*)lds, 16, 0, 0);
}

// ---------------------------------------------------------------------------
// One fused fp32 -> bf16 cast for x + 4 weights (contiguous dst in ws).
// ---------------------------------------------------------------------------
__global__ __launch_bounds__(256) void cast_all(const float* __restrict__ x,
                                                const float* __restrict__ wq,
                                                const float* __restrict__ wk,
                                                const float* __restrict__ wv,
                                                const float* __restrict__ wo,
                                                unsigned short* __restrict__ dst) {
    const size_t NE = (size_t)M_TOTAL * D_MODEL;
    const size_t WE = (size_t)D_MODEL * D_MODEL;
    size_t i4 = (size_t)blockIdx.x * 256 + threadIdx.x;
    size_t e = i4 * 4;
    const float* src; size_t off;
    if (e < NE) { src = x; off = e; }
    else {
        size_t t = e - NE;
        int r = (int)(t / WE); off = t - (size_t)r * WE;
        src = (r == 0) ? wq : (r == 1) ? wk : (r == 2) ? wv : wo;
    }
    float4 v = *(const float4*)(src + off);
    ushort4 o;
    o.x = f2bu(v.x); o.y = f2bu(v.y); o.z = f2bu(v.z); o.w = f2bu(v.w);
    ((ushort4*)dst)[i4] = o;
}

// ---------------------------------------------------------------------------
// Fused Q/K/V projection. Round-12: double-buffered single-barrier K loop
// (flash-proven schedule): issue tile kt+1 -> buf^1 via global_load_lds,
// compute tile kt from buf, ONE __syncthreads per iter (its built-in
// vmcnt(0) drains loads that overlapped the whole compute; same barrier
// fences buffer reuse). Barriers 64 -> 32; staging latency fully hidden.
// Retains r8: 128x128 tile, BK=32, XOR chunk swizzle, T1 XCD remap.
// ---------------------------------------------------------------------------
__global__ __launch_bounds__(256) void qkv_gemm(const unsigned short* __restrict__ X,
                                                const unsigned short* __restrict__ W0,
                                                const unsigned short* __restrict__ W1,
                                                const unsigned short* __restrict__ W2,
                                                unsigned short* __restrict__ Y0,
                                                unsigned short* __restrict__ Y1,
                                                unsigned short* __restrict__ Vt) {
    __shared__ short As[2][128 * 32];
    __shared__ short Bs[2][128 * 32];

    const int id = (int)blockIdx.x + 24 * (int)blockIdx.y;
    const int xcd = id & 7, slot = id >> 3;
    const int ty = xcd * 8 + slot / 24;        // row tile 0..63 (XCD-clustered)
    const int tx = slot % 24;                  // sel*8 + col tile

    const int sel = tx >> 3;
    const unsigned short* W = (sel == 0) ? W0 : (sel == 1) ? W1 : W2;
    const float scl = (sel == 0) ? Q_SCALE : 1.0f;

    const int tid = threadIdx.x;
    const int w = tid >> 6, lane = tid & 63, quad = lane >> 4, l15 = lane & 15;
    const int wm = w & 1, wn = w >> 1;
    const int rowBase = ty * 128;
    const int colBase = (tx & 7) * 128;

    // staging constants (chunk c = tid + l*256): row, swizzled source chunk
    int stRow[2], stCc[2];
#pragma unroll
    for (int l = 0; l < 2; ++l) {
        int c = tid + l * 256;
        stRow[l] = c >> 2;
        stCc[l] = (c & 3) ^ ((stRow[l] >> 1) & 3);
    }

    f32x4 acc[4][4];
#pragma unroll
    for (int mi = 0; mi < 4; ++mi)
#pragma unroll
        for (int ni = 0; ni < 4; ++ni)
#pragma unroll
            for (int e = 0; e < 4; ++e) acc[mi][ni][e] = 0.f;

    // ---- prologue: issue tile 0 into buf 0 ----
#pragma unroll
    for (int l = 0; l < 2; ++l) {
        int c = tid + l * 256;
        async16((char*)As[0] + c * 16, X + (size_t)(rowBase + stRow[l]) * 1024 + stCc[l] * 8);
        async16((char*)Bs[0] + c * 16, W + (size_t)(colBase + stRow[l]) * 1024 + stCc[l] * 8);
    }
    __syncthreads();                           // drains vmcnt -> tile 0 visible

    for (int kt = 0; kt < 32; ++kt) {
        const int buf = kt & 1;
        if (kt < 31) {                         // issue tile kt+1 (overlaps compute)
            const int kn = (kt + 1) * 32;
#pragma unroll
            for (int l = 0; l < 2; ++l) {
                int c = tid + l * 256;
                async16((char*)As[buf ^ 1] + c * 16,
                        X + (size_t)(rowBase + stRow[l]) * 1024 + kn + stCc[l] * 8);
                async16((char*)Bs[buf ^ 1] + c * 16,
                        W + (size_t)(colBase + stRow[l]) * 1024 + kn + stCc[l] * 8);
            }
        }

        bf16x8 a[4], b[4];
#pragma unroll
        for (int mi = 0; mi < 4; ++mi) {
            int r = wm * 64 + mi * 16 + l15;
            int slt = quad ^ ((r >> 1) & 3);
            a[mi] = *(const bf16x8*)&As[buf][r * 32 + slt * 8];
        }
#pragma unroll
        for (int ni = 0; ni < 4; ++ni) {
            int r = wn * 64 + ni * 16 + l15;
            int slt = quad ^ ((r >> 1) & 3);
            b[ni] = *(const bf16x8*)&Bs[buf][r * 32 + slt * 8];
        }
#pragma unroll
        for (int mi = 0; mi < 4; ++mi)
#pragma unroll
            for (int ni = 0; ni < 4; ++ni)
                acc[mi][ni] = __builtin_amdgcn_mfma_f32_16x16x32_bf16(a[mi], b[ni], acc[mi][ni], 0, 0, 0);

        __syncthreads();                       // drains my kt+1 loads; fences buf reuse
    }

    if (sel != 2) {
        unsigned short* Y = (sel == 0) ? Y0 : Y1;
#pragma unroll
        for (int mi = 0; mi < 4; ++mi)
#pragma unroll
            for (int ni = 0; ni < 4; ++ni)
#pragma unroll
                for (int reg = 0; reg < 4; ++reg) {
                    int row = rowBase + wm * 64 + mi * 16 + quad * 4 + reg;
                    int col = colBase + wn * 64 + ni * 16 + l15;
                    Y[(size_t)row * 1024 + col] = f2bu(acc[mi][ni][reg] * scl);
                }
    } else {
        // transposed V write: Vt[((b*16+h)*64+d)*SEQ + s], 4 consecutive s per store
#pragma unroll
        for (int mi = 0; mi < 4; ++mi) {
            int row0 = rowBase + wm * 64 + mi * 16 + quad * 4;   // reg 0 row
            int bb = row0 >> 11;
            int s0 = row0 & 2047;
#pragma unroll
            for (int ni = 0; ni < 4; ++ni) {
                int col = colBase + wn * 64 + ni * 16 + l15;
                int hh = col >> 6, dd = col & 63;
                ushort4 pk;
                pk.x = f2bu(acc[mi][ni][0]); pk.y = f2bu(acc[mi][ni][1]);
                pk.z = f2bu(acc[mi][ni][2]); pk.w = f2bu(acc[mi][ni][3]);
                *(ushort4*)(Vt + (((size_t)bb * 16 + hh) * 64 + dd) * SEQ + s0) = pk;
            }
        }
    }
}

// ---------------------------------------------------------------------------
// Output projection: same round-12 single-barrier dbuf restructure.
// Retains r8 T1 XCD remap.
// ---------------------------------------------------------------------------
__global__ __launch_bounds__(256) void out_gemm(const unsigned short* __restrict__ X,
                                                const unsigned short* __restrict__ W,
                                                float* __restrict__ Y) {
    __shared__ short As[2][128 * 32];
    __shared__ short Bs[2][128 * 32];

    const int id = (int)blockIdx.x + 8 * (int)blockIdx.y;
    const int xcd = id & 7, slot = id >> 3;
    const int ty = xcd * 8 + (slot >> 3);
    const int tx = slot & 7;

    const int tid = threadIdx.x;
    const int w = tid >> 6, lane = tid & 63, quad = lane >> 4, l15 = lane & 15;
    const int wm = w & 1, wn = w >> 1;
    const int rowBase = ty * 128;
    const int colBase = tx * 128;

    int stRow[2], stCc[2];
#pragma unroll
    for (int l = 0; l < 2; ++l) {
        int c = tid + l * 256;
        stRow[l] = c >> 2;
        stCc[l] = (c & 3) ^ ((stRow[l] >> 1) & 3);
    }

    f32x4 acc[4][4];
#pragma unroll
    for (int mi = 0; mi < 4; ++mi)
#pragma unroll
        for (int ni = 0; ni < 4; ++ni)
#pragma unroll
            for (int e = 0; e < 4; ++e) acc[mi][ni][e] = 0.f;

    // ---- prologue: issue tile 0 into buf 0 ----
#pragma unroll
    for (int l = 0; l < 2; ++l) {
        int c = tid + l * 256;
        async16((char*)As[0] + c * 16, X + (size_t)(rowBase + stRow[l]) * 1024 + stCc[l] * 8);
        async16((char*)Bs[0] + c * 16, W + (size_t)(colBase + stRow[l]) * 1024 + stCc[l] * 8);
    }
    __syncthreads();

    for (int kt = 0; kt < 32; ++kt) {
        const int buf = kt & 1;
        if (kt < 31) {
            const int kn = (kt + 1) * 32;
#pragma unroll
            for (int l = 0; l < 2; ++l) {
                int c = tid + l * 256;
                async16((char*)As[buf ^ 1] + c * 16,
                        X + (size_t)(rowBase + stRow[l]) * 1024 + kn + stCc[l] * 8);
                async16((char*)Bs[buf ^ 1] + c * 16,
                        W + (size_t)(colBase + stRow[l]) * 1024 + kn + stCc[l] * 8);
            }
        }

        bf16x8 a[4], b[4];
#pragma unroll
        for (int mi = 0; mi < 4; ++mi) {
            int r = wm * 64 + mi * 16 + l15;
            int slt = quad ^ ((r >> 1) & 3);
            a[mi] = *(const bf16x8*)&As[buf][r * 32 + slt * 8];
        }
#pragma unroll
        for (int ni = 0; ni < 4; ++ni) {
            int r = wn * 64 + ni * 16 + l15;
            int slt = quad ^ ((r >> 1) & 3);
            b[ni] = *(const bf16x8*)&Bs[buf][r * 32 + slt * 8];
        }
#pragma unroll
        for (int mi = 0; mi < 4; ++mi)
#pragma unroll
            for (int ni = 0; ni < 4; ++ni)
                acc[mi][ni] = __builtin_amdgcn_mfma_f32_16x16x32_bf16(a[mi], b[ni], acc[mi][ni], 0, 0, 0);

        __syncthreads();
    }

#pragma unroll
    for (int mi = 0; mi < 4; ++mi)
#pragma unroll
        for (int ni = 0; ni < 4; ++ni)
#pragma unroll
            for (int reg = 0; reg < 4; ++reg) {
                int row = rowBase + wm * 64 + mi * 16 + quad * 4 + reg;
                int col = colBase + wn * 64 + ni * 16 + l15;
                Y[(size_t)row * 1024 + col] = acc[mi][ni][reg];
            }
}

// ---------------------------------------------------------------------------
// Flash attention — byte-identical to rounds 5/8 (PASSED, ~126 us):
//   KVBLK=64, St[2], paired q-tiles {15-pid,pid} (36 iters, perfect balance),
//   XCD-local grid (64,8), double-buffered K/V with ONE barrier per tile,
//   wave-uniform triangle guards, defer-max THR=8, v_cvt_pk pack,
//   allSeq fast path, setprio around MFMA clusters.
// (Dead ends, do not retry: V-direct-from-global [r6/r7 absmax 6.08];
//  KV-split occupancy [r9/r10: unified VGPR>128 caps 2 blocks/CU];
//  8-phase 256^2 qkv [r11: parity — 384-block grid = 1.5 blocks/CU
//  imbalance eats the schedule gain].)
// ---------------------------------------------------------------------------
__global__ __launch_bounds__(256) void flash32(const unsigned short* __restrict__ Q,
                                               const unsigned short* __restrict__ K,
                                               const unsigned short* __restrict__ Vt,
                                               const int* __restrict__ mask,
                                               unsigned short* __restrict__ CTX) {
    __shared__ short lds[16384];           // K dbuf [0..8191], V dbuf [8192..16383] (shorts)
    __shared__ float biasS[2][64];
    __shared__ int allokS[2];
    __shared__ int okW[4];

    const int bh = blockIdx.x;             // 0..63 (same-bh blocks share an XCD)
    const int pid = blockIdx.y;            // 0..7
    const int b = bh >> 4;
    const int tid = threadIdx.x;
    const int w = tid >> 6, lane = tid & 63, l31 = lane & 31, lane5 = lane >> 5;

    const size_t qkBase = (size_t)b * SEQ * D_MODEL + (size_t)(bh & 15) * HEAD_DIM;
    const size_t vtBase = (size_t)bh * HEAD_DIM * SEQ;

    // ---- attention_mask is k-loop invariant: scan it once per block ----
    {
        int ok = 1;
        for (int i = tid; i < SEQ; i += 256) ok &= (mask[b * SEQ + i] != 0);
        unsigned long long bal = __ballot(ok != 0);
        if (lane == 0) okW[w] = (bal == ~0ull) ? 1 : 0;
    }
    __syncthreads();
    const int allSeq = okW[0] & okW[1] & okW[2] & okW[3];   // block-uniform

    // per-thread staging constants (chunk c = tid + l*256)
    int stp[2], stcc[2], stj[2];
#pragma unroll
    for (int l = 0; l < 2; ++l) {
        int c = tid + l * 256;
        int p = c >> 3, sl = c & 7;
        stp[l] = p;
        stcc[l] = sl ^ (p & 7);                                   // bank swizzle
        stj[l] = (p & 0x33) | ((p & 4) << 1) | ((p & 8) >> 1);    // swap bits 2,3
    }

    for (int phase = 0; phase < 2; ++phase) {
        const int qt = phase ? pid : 15 - pid;
        const int q0 = qt * 128;
        const int iq = q0 + w * 32 + l31;      // this lane's query row

        // Q fragments direct from global: B[n=i=l31][k=lane5*8+jj]
        bf16x8 qf[4];
#pragma unroll
        for (int ks = 0; ks < 4; ++ks)
            qf[ks] = *(const bf16x8*)(Q + qkBase + (size_t)iq * D_MODEL + ks * 16 + lane5 * 8);

        float mv = -INFINITY, lv = 0.f;
        f32x16 Ot[2];
#pragma unroll
        for (int dt = 0; dt < 2; ++dt)
#pragma unroll
            for (int e = 0; e < 16; ++e) Ot[dt][e] = 0.f;

        const int ktmax = 2 * qt + 1;

        uint4 kreg[2], vreg[2];
        int mreg = 1;
        // prefetch tile 0
#pragma unroll
        for (int l = 0; l < 2; ++l) {
            kreg[l] = *(const uint4*)(K + qkBase + (size_t)stj[l] * D_MODEL + stcc[l] * 8);
            vreg[l] = *(const uint4*)(Vt + vtBase + (size_t)stp[l] * SEQ + stcc[l] * 8);
        }
        if (!allSeq && tid < 64) mreg = mask[b * SEQ + tid];

        for (int kt = 0; kt <= ktmax; ++kt) {
            const int k0 = kt * 64;
            const int buf = kt & 1;
            // ---- stage tile kt into buf (regs -> LDS), prefetch kt+1 ----
#pragma unroll
            for (int l = 0; l < 2; ++l) {
                int c = tid + l * 256;
                *(uint4*)((char*)lds + buf * 8192 + c * 16) = kreg[l];
                *(uint4*)((char*)lds + 16384 + buf * 8192 + c * 16) = vreg[l];
            }
            if (!allSeq && tid < 64) {
                biasS[buf][tid] = mreg ? 0.f : -INFINITY;
                unsigned long long bal = __ballot(mreg != 0);
                if (tid == 0) allokS[buf] = (bal == ~0ull) ? 1 : 0;
            }
            if (kt < ktmax) {                  // prefetch next tile (overlaps compute)
                const int kn = k0 + 64;
#pragma unroll
                for (int l = 0; l < 2; ++l) {
                    kreg[l] = *(const uint4*)(K + qkBase + (size_t)(kn + stj[l]) * D_MODEL + stcc[l] * 8);
                    vreg[l] = *(const uint4*)(Vt + vtBase + (size_t)stp[l] * SEQ + kn + stcc[l] * 8);
                }
                if (!allSeq && tid < 64) mreg = mask[b * SEQ + kn + tid];
            }
            __syncthreads();                   // buf visible; buf reuse fenced by barrier(kt+1)

            if (64 * kt > q0 + 32 * w + 31) continue;   // wave-uniform: tile above causal diag

            const short* Ks = lds + buf * 4096;
            const short* Vs = lds + 8192 + buf * 4096;

            // wave-uniform active range (diagonal tile triangle)
            const int kHi = q0 + 32 * w + 31 - k0;           // >= 0 here
            const int nT = (kHi >= 32) ? 2 : 1;              // active 32-key QK sub-tiles
            const int nt = ((kHi >> 4) >= 3 ? 3 : (kHi >> 4)) + 1;  // active 16-key PV slots

            // ---- St = K Q^T (up to 8 MFMAs) -----------------------------
            f32x16 St[2];
            __builtin_amdgcn_s_setprio(1);
#pragma unroll
            for (int T = 0; T < 2; ++T) {
                if (T < nT) {
#pragma unroll
                    for (int e = 0; e < 16; ++e) St[T][e] = 0.f;
#pragma unroll
                    for (int ks = 0; ks < 4; ++ks) {
                        int p = T * 32 + l31;
                        int slot = (ks * 2 + lane5) ^ (p & 7);
                        bf16x8 a = *(const bf16x8*)&Ks[p * 64 + slot * 8];
                        St[T] = __builtin_amdgcn_mfma_f32_32x32x16_bf16(a, qf[ks], St[T], 0, 0, 0);
                    }
                }
            }
            __builtin_amdgcn_s_setprio(0);

            // ---- masking ------------------------------------------------
            const bool partial = (k0 + 63 > q0 + 32 * w);
            if (partial) {
#pragma unroll
                for (int T = 0; T < 2; ++T)
                    if (T < nT)
#pragma unroll
                        for (int r = 0; r < 16; ++r) {
                            int j = k0 + 32 * T + 16 * (r >> 3) + 8 * lane5 + (r & 7);
                            if (j > iq) St[T][r] = -INFINITY;
                        }
            }
            if (!allSeq && !allokS[buf]) {
#pragma unroll
                for (int T = 0; T < 2; ++T)
                    if (T < nT)
#pragma unroll
                        for (int r = 0; r < 16; ++r)
                            St[T][r] += biasS[buf][32 * T + 16 * (r >> 3) + 8 * lane5 + (r & 7)];
            }

            // ---- online softmax (defer-max THR=8, per-lane state) -------
            float tm[2];
#pragma unroll
            for (int T = 0; T < 2; ++T) {
                if (T < nT) {
                    float a0 = fmaxf(fmaxf(St[T][0], St[T][1]), fmaxf(St[T][2], St[T][3]));
                    float a1 = fmaxf(fmaxf(St[T][4], St[T][5]), fmaxf(St[T][6], St[T][7]));
                    float a2 = fmaxf(fmaxf(St[T][8], St[T][9]), fmaxf(St[T][10], St[T][11]));
                    float a3 = fmaxf(fmaxf(St[T][12], St[T][13]), fmaxf(St[T][14], St[T][15]));
                    tm[T] = fmaxf(fmaxf(a0, a1), fmaxf(a2, a3));
                } else tm[T] = -INFINITY;
            }
            float rm = fmaxf(tm[0], tm[1]);
            rm = fmaxf(rm, __shfl_xor(rm, 32));
            float mn = fmaxf(mv, rm);
            if (mn > mv + 8.f) {               // rare after warmup (also hits 1st tile)
                float al = exp2f(mv - mn);     // mv=-inf -> 0: correctly zeroes lv/Ot
                lv *= al;
#pragma unroll
                for (int dt = 0; dt < 2; ++dt)
#pragma unroll
                    for (int e = 0; e < 16; ++e) Ot[dt][e] *= al;
                mv = mn;
            }
            // exp2 vs (possibly stale) mv: P bounded by 2^8; -inf scores -> 0
            float rsp[2] = {0.f, 0.f};
#pragma unroll
            for (int T = 0; T < 2; ++T) {
                if (T < nT) {
#pragma unroll
                    for (int r = 0; r < 16; ++r) {
                        float pv = exp2f(St[T][r] - mv);
                        St[T][r] = pv;
                        rsp[T] += pv;
                    }
                }
            }
            float rs = rsp[0] + rsp[1];
            rs += __shfl_xor(rs, 32);
            lv += rs;

            // ---- pack P via v_cvt_pk_bf16_f32 (regs already B-frag order)
            bf16x8 pf[4];
#pragma unroll
            for (int t = 0; t < 4; ++t) {
                if (t < nt) {
                    const int T = t >> 1, hb = t & 1;
                    unsigned u0, u1, u2, u3;
                    asm("v_cvt_pk_bf16_f32 %0, %1, %2" : "=v"(u0)
                        : "v"(St[T][hb * 8 + 0]), "v"(St[T][hb * 8 + 1]));
                    asm("v_cvt_pk_bf16_f32 %0, %1, %2" : "=v"(u1)
                        : "v"(St[T][hb * 8 + 2]), "v"(St[T][hb * 8 + 3]));
                    asm("v_cvt_pk_bf16_f32 %0, %1, %2" : "=v"(u2)
                        : "v"(St[T][hb * 8 + 4]), "v"(St[T][hb * 8 + 5]));
                    asm("v_cvt_pk_bf16_f32 %0, %1, %2" : "=v"(u3)
                        : "v"(St[T][hb * 8 + 6]), "v"(St[T][hb * 8 + 7]));
                    union { unsigned u[4]; bf16x8 v; } pk;
                    pk.u[0] = u0; pk.u[1] = u1; pk.u[2] = u2; pk.u[3] = u3;
                    pf[t] = pk.v;
                }
            }

            // ---- Ot += V^T P^T (up to 8 MFMAs) --------------------------
            __builtin_amdgcn_s_setprio(1);
#pragma unroll
            for (int dt = 0; dt < 2; ++dt)
#pragma unroll
                for (int t = 0; t < 4; ++t) {
                    if (t < nt) {
                        int p = dt * 32 + l31;
                        int slot = (t * 2 + lane5) ^ (p & 7);
                        bf16x8 a = *(const bf16x8*)&Vs[p * 64 + slot * 8];
                        Ot[dt] = __builtin_amdgcn_mfma_f32_32x32x16_bf16(a, pf[t], Ot[dt], 0, 0, 0);
                    }
                }
            __builtin_amdgcn_s_setprio(0);
        }

        // ---- epilogue: normalize, transpose via LDS, coalesced store ----
        __syncthreads();                       // all waves done with K/V buffers
        const float inv = 1.f / lv;
#pragma unroll
        for (int dt = 0; dt < 2; ++dt)
#pragma unroll
            for (int k = 0; k < 8; ++k) {
                int r0 = 2 * k;
                int d = (r0 & 3) + 4 * lane5 + 8 * (r0 >> 2) + 32 * dt;
                unsigned lo = f2bu(Ot[dt][r0] * inv);
                unsigned hi = f2bu(Ot[dt][r0 + 1] * inv);
                *(unsigned*)&lds[(w * 32 + l31) * 72 + d] = lo | (hi << 16);
            }
        __syncthreads();
#pragma unroll
        for (int k = 0; k < 4; ++k) {
            int id = tid + k * 256;
            int r = id >> 3, cc = id & 7;
            uint4 v = *(const uint4*)&lds[r * 72 + cc * 8];
            *(uint4*)(CTX + qkBase + (size_t)(q0 + r) * D_MODEL + cc * 8) = v;
        }
        __syncthreads();                       // protect epilogue reads from next phase's staging
    }
}

// ---------------------------------------------------------------------------
extern "C" void kernel_launch(void* const* d_in, const int* in_sizes, int n_in,
                              void* d_out, int out_size, void* d_ws, size_t ws_size,
                              hipStream_t stream) {
    const float* x  = (const float*)d_in[0];
    const int* mask = (const int*)d_in[1];
    const float* wq = (const float*)d_in[2];
    const float* wk = (const float*)d_in[3];
    const float* wv = (const float*)d_in[4];
    const float* wo = (const float*)d_in[5];
    float* out = (float*)d_out;

    const size_t NE = (size_t)M_TOTAL * D_MODEL;
    const size_t WE = (size_t)D_MODEL * D_MODEL;
    unsigned short* ws  = (unsigned short*)d_ws;
    unsigned short* xb  = ws;
    unsigned short* wqb = xb + NE;
    unsigned short* wkb = wqb + WE;
    unsigned short* wvb = wkb + WE;
    unsigned short* wob = wvb + WE;
    unsigned short* Qb  = wob + WE;
    unsigned short* Kb  = Qb + NE;
    unsigned short* Vtb = Kb + NE;
    unsigned short* CTX = Vtb + NE;

    cast_all<<<(int)((NE + 4 * WE) / 4 / 256), 256, 0, stream>>>(x, wq, wk, wv, wo, ws);

    qkv_gemm<<<dim3(24, M_TOTAL / 128), 256, 0, stream>>>(xb, wqb, wkb, wvb, Qb, Kb, Vtb);

    flash32<<<dim3(64, 8), 256, 0, stream>>>(Qb, Kb, Vtb, mask, CTX);

    out_gemm<<<dim3(D_MODEL / 128, M_TOTAL / 128), 256, 0, stream>>>(CTX, wob, out);
}